// Round 10
// baseline (924.037 us; speedup 1.0000x reference)
//
#include <hip/hip_runtime.h>
#include <hip/hip_bf16.h>

#define N_NODES 50000
#define N_EDGES 800000
#define NUM_MOL 2000

typedef __attribute__((ext_vector_type(8))) short short8;
typedef __attribute__((ext_vector_type(4))) float f32x4;

union bfbits { __hip_bfloat16 b; short s; };

// ---------------------------------------------------------------------------
// Type tables.
// ---------------------------------------------------------------------------
__global__ void k_tables(const float* __restrict__ atom_table,
                         const float* __restrict__ bond_table,
                         const float* __restrict__ Wi,
                         const float* __restrict__ bi,
                         const float* __restrict__ Wu1,
                         const float* __restrict__ bu1,
                         float* __restrict__ T1, float* __restrict__ U1,
                         float* __restrict__ T2c, float* __restrict__ U2c) {
  int b = blockIdx.x;
  int c = threadIdx.x;
  if (b < 119) {
    float t = 0.f, u = 0.f;
    for (int k = 0; k < 128; k++) {
      float a = atom_table[b * 128 + k];
      t += a * Wi[k * 128 + c];
      u += a * Wu1[k * 128 + c];
    }
    T1[b * 128 + c] = t;
    U1[b * 128 + c] = u;
  } else {
    int a = b - 119;
    float t = bi[c], u = bu1[c];
    for (int k = 0; k < 64; k++) {
      float bv = bond_table[a * 64 + k];
      t += bv * Wi[(128 + k) * 128 + c];
      u += bv * Wu1[(128 + k) * 128 + c];
    }
    T2c[a * 128 + c] = t;
    U2c[a * 128 + c] = u;
  }
}

// TT[x*4+a, c] = relu(T1[x,c] + T2c[a,c])
__global__ void k_tt(const float* __restrict__ T1, const float* __restrict__ T2c,
                     float* __restrict__ TT) {
  int r = blockIdx.x;   // 0..475
  int c = threadIdx.x;
  float v = T1[(r >> 2) * 128 + c] + T2c[(r & 3) * 128 + c];
  TT[r * 128 + c] = v > 0.f ? v : 0.f;
}

// Wt/Wlo: hi/lo bf16 split of Wu2^T for MFMA B-frags.
__global__ void k_wt(const float* __restrict__ Wu2, short* __restrict__ Wt,
                     short* __restrict__ Wlo) {
  int n = blockIdx.x;
  int k = threadIdx.x;
  float w = Wu2[k * 128 + n];
  bfbits hi; hi.b = __float2bfloat16(w);
  float hf = __bfloat162float(hi.b);
  bfbits lo; lo.b = __float2bfloat16(w - hf);
  Wt[n * 128 + k] = hi.s;
  Wlo[n * 128 + k] = lo.s;
}

// ---------------------------------------------------------------------------
// CSR build: histogram, 3-phase multi-block scan, fill (csr + csr0).
// ---------------------------------------------------------------------------
__global__ void k_hist(const int* __restrict__ eidx, int* __restrict__ cnt) {
  int e = blockIdx.x * 256 + threadIdx.x;
  atomicAdd(&cnt[eidx[N_EDGES + e]], 1);
}

__global__ __launch_bounds__(1024) void k_scanA(const int* __restrict__ cnt,
                                                int* __restrict__ locinc,
                                                int* __restrict__ partial) {
  __shared__ int buf[1024];
  int t = threadIdx.x;
  int i = blockIdx.x * 1024 + t;
  int v = (i < N_NODES) ? cnt[i] : 0;
  buf[t] = v;
  __syncthreads();
  for (int off = 1; off < 1024; off <<= 1) {
    int add = (t >= off) ? buf[t - off] : 0;
    __syncthreads();
    buf[t] += add;
    __syncthreads();
  }
  if (i < N_NODES) locinc[i] = buf[t];
  if (t == 1023) partial[blockIdx.x] = buf[t];
}

__global__ void k_scanB(const int* __restrict__ partial, int* __restrict__ offs) {
  int lane = threadIdx.x;   // 64 threads
  int v = (lane < 49) ? partial[lane] : 0;
  int inc = v;
  for (int d = 1; d < 64; d <<= 1) {
    int u = __shfl_up(inc, d, 64);
    if (lane >= d) inc += u;
  }
  if (lane < 49) offs[lane] = inc - v;   // exclusive
}

__global__ void k_scanC(const int* __restrict__ cnt, const int* __restrict__ locinc,
                        const int* __restrict__ offs,
                        int* __restrict__ rowptr, int* __restrict__ cursor) {
  int i = blockIdx.x * 256 + threadIdx.x;
  if (i < N_NODES) {
    int rp = locinc[i] + offs[i >> 10];
    rowptr[i + 1] = rp;
    cursor[i] = rp - cnt[i];
    if (i == 0) rowptr[0] = 0;
  }
}

__global__ void k_fill(const int* __restrict__ eidx, const int* __restrict__ attr,
                       const int* __restrict__ x,
                       int* __restrict__ cursor, int* __restrict__ csr,
                       int* __restrict__ csr0) {
  int e = blockIdx.x * 256 + threadIdx.x;
  int d = eidx[N_EDGES + e];
  int s = eidx[e];
  int a = attr[e];
  int pos = atomicAdd(&cursor[d], 1);
  csr[pos] = s * 4 + a;
  csr0[pos] = x[s] * 4 + a;
}

// molptr[m] = lower_bound(batch, m)
__global__ void k_molptr(const int* __restrict__ batch, int* __restrict__ molptr) {
  int m = blockIdx.x * 256 + threadIdx.x;
  if (m > NUM_MOL) return;
  int lo = 0, hi = N_NODES;
  while (lo < hi) {
    int mid = (lo + hi) >> 1;
    if (batch[mid] < m) lo = mid + 1; else hi = mid;
  }
  molptr[m] = lo;
}

// ---------------------------------------------------------------------------
// Gather initial messages: A[n] = sum TT[csr0[i]]  (fp32 rows, 512 B).
// 2 rows per VMEM inst: lane g=lane>>5 handles rows i+g, p=lane&31 handles
// channels p*4..p*4+3 (16 B/lane). Butterfly XOR 32 combines the two halves.
// ---------------------------------------------------------------------------
__global__ void k_gather0(const int* __restrict__ rowptr, const int* __restrict__ csr0,
                          const float* __restrict__ TT, float* __restrict__ A_) {
  int n = blockIdx.x * 4 + (threadIdx.x >> 6);
  int lane = threadIdx.x & 63;
  int g = lane >> 5;        // 0..1
  int p = lane & 31;        // channel quad
  int beg = rowptr[n], end = rowptr[n + 1];
  float s0 = 0.f, s1 = 0.f, s2 = 0.f, s3 = 0.f;
  int i = beg;
  for (; i + 3 < end; i += 4) {
    int idxA = csr0[i + g];
    int idxB = csr0[i + 2 + g];
    float4 va = *(const float4*)&TT[idxA * 128 + p * 4];
    float4 vb = *(const float4*)&TT[idxB * 128 + p * 4];
    s0 += va.x + vb.x; s1 += va.y + vb.y;
    s2 += va.z + vb.z; s3 += va.w + vb.w;
  }
  for (; i < end; i += 2) {
    if (i + g < end) {
      int idx = csr0[i + g];
      float4 v = *(const float4*)&TT[idx * 128 + p * 4];
      s0 += v.x; s1 += v.y; s2 += v.z; s3 += v.w;
    }
  }
  s0 += __shfl_xor(s0, 32, 64);
  s1 += __shfl_xor(s1, 32, 64);
  s2 += __shfl_xor(s2, 32, 64);
  s3 += __shfl_xor(s3, 32, 64);
  // lane writes channels p*4 + g*2, p*4 + g*2 + 1
  float2 o;
  o.x = (g == 0) ? s0 : s2;
  o.y = (g == 0) ? s1 : s3;
  *(float2*)&A_[n * 128 + p * 4 + g * 2] = o;
}

// ---------------------------------------------------------------------------
// Gather messages: A[n] = sum M_bf16[csr[i]]  (256 B rows).
// 4 rows per VMEM inst: g=lane>>4 handles rows i+g, p=lane&15 handles
// channels p*8..p*8+7 (16 B/lane). Butterflies XOR 16, 32 combine.
// ---------------------------------------------------------------------------
__global__ void k_gather(const int* __restrict__ rowptr, const int* __restrict__ csr,
                         const __hip_bfloat16* __restrict__ M, float* __restrict__ A_) {
  int n = blockIdx.x * 4 + (threadIdx.x >> 6);
  int lane = threadIdx.x & 63;
  int g = lane >> 4;        // 0..3
  int p = lane & 15;        // channel octet
  int beg = rowptr[n], end = rowptr[n + 1];
  float s[8];
#pragma unroll
  for (int j = 0; j < 8; j++) s[j] = 0.f;
  const short* Ms = (const short*)M;
  int i = beg;
  for (; i + 7 < end; i += 8) {
    int idxA = csr[i + g];
    int idxB = csr[i + 4 + g];
    short8 va = *(const short8*)&Ms[idxA * 128 + p * 8];
    short8 vb = *(const short8*)&Ms[idxB * 128 + p * 8];
#pragma unroll
    for (int j = 0; j < 4; j++) {
      float2 fa = __bfloat1622float2(*(const __hip_bfloat162*)&((const short*)&va)[j * 2]);
      float2 fb = __bfloat1622float2(*(const __hip_bfloat162*)&((const short*)&vb)[j * 2]);
      s[j * 2] += fa.x + fb.x;
      s[j * 2 + 1] += fa.y + fb.y;
    }
  }
  for (; i < end; i += 4) {
    if (i + g < end) {
      int idx = csr[i + g];
      short8 va = *(const short8*)&Ms[idx * 128 + p * 8];
#pragma unroll
      for (int j = 0; j < 4; j++) {
        float2 fa = __bfloat1622float2(*(const __hip_bfloat162*)&((const short*)&va)[j * 2]);
        s[j * 2] += fa.x;
        s[j * 2 + 1] += fa.y;
      }
    }
  }
#pragma unroll
  for (int j = 0; j < 8; j++) s[j] += __shfl_xor(s[j], 16, 64);
#pragma unroll
  for (int j = 0; j < 8; j++) s[j] += __shfl_xor(s[j], 32, 64);
  // lane writes channels p*8 + g*2, p*8 + g*2 + 1
  float2 o;
  o.x = s[g * 2];
  o.y = s[g * 2 + 1];
  *(float2*)&A_[n * 128 + p * 8 + g * 2] = o;
}

// ---------------------------------------------------------------------------
// k_mm1: B = A @ Wu1[192:320,:]  fp32 tiled GEMM.
// ---------------------------------------------------------------------------
__global__ __launch_bounds__(256, 4) void k_mm1(const float* __restrict__ A_,
                                                const float* __restrict__ Wu1,
                                                float* __restrict__ B_) {
  __shared__ float Hs[64][132];
  int t = threadIdx.x;
  int base = blockIdx.x * 64;
#pragma unroll
  for (int j = 0; j < 8; j++) {
    int idx = j * 256 + t;
    int rr = idx >> 5;
    int kq = idx & 31;
    int n = base + rr;
    if (n >= N_NODES) n = N_NODES - 1;
    float4 v = *(const float4*)&A_[n * 128 + kq * 4];
    *(float4*)&Hs[rr][kq * 4] = v;
  }
  __syncthreads();
  int r0 = (t >> 4) * 4;
  int c0 = (t & 15) * 8;
  const float* W = Wu1 + 192 * 128;
  float acc[4][8];
#pragma unroll
  for (int r = 0; r < 4; r++)
#pragma unroll
    for (int j = 0; j < 8; j++) acc[r][j] = 0.f;
#pragma unroll 2
  for (int kq = 0; kq < 32; kq++) {
    const int k = kq * 4;
    float h0[4], h1[4], h2[4], h3[4];
    *(float4*)h0 = *(const float4*)&Hs[r0][k];
    *(float4*)h1 = *(const float4*)&Hs[r0 + 1][k];
    *(float4*)h2 = *(const float4*)&Hs[r0 + 2][k];
    *(float4*)h3 = *(const float4*)&Hs[r0 + 3][k];
#pragma unroll
    for (int i = 0; i < 4; i++) {
      float w[8];
      *(float4*)&w[0] = *(const float4*)&W[(k + i) * 128 + c0];
      *(float4*)&w[4] = *(const float4*)&W[(k + i) * 128 + c0 + 4];
      float hv[4] = {h0[i], h1[i], h2[i], h3[i]};
#pragma unroll
      for (int r = 0; r < 4; r++)
#pragma unroll
        for (int j = 0; j < 8; j++) acc[r][j] += hv[r] * w[j];
    }
  }
#pragma unroll
  for (int r = 0; r < 4; r++) {
    int n = base + r0 + r;
    if (n < N_NODES) {
      float4 o0, o1;
      o0.x = acc[r][0]; o0.y = acc[r][1]; o0.z = acc[r][2]; o0.w = acc[r][3];
      o1.x = acc[r][4]; o1.y = acc[r][5]; o1.z = acc[r][6]; o1.w = acc[r][7];
      *(float4*)&B_[n * 128 + c0] = o0;
      *(float4*)&B_[n * 128 + c0 + 4] = o1;
    }
  }
}

// ---------------------------------------------------------------------------
// k_mm2 v5 (4 waves per slab, 32 ch each): whi+wlo = 64 VGPRs per wave ->
// fits __launch_bounds__(256,4) for 16 waves/CU. Grid 1024 = 4 blocks/CU
// resident; 13 slab iterations. D = ahi@Whi + alo@Whi + ahi@Wlo.
// ---------------------------------------------------------------------------
__global__ __launch_bounds__(256, 4) void k_mm2(const float* __restrict__ B_,
                                                const int* __restrict__ x,
                                                const float* __restrict__ U1,
                                                const float* __restrict__ U2c,
                                                const short* __restrict__ Wt,
                                                const short* __restrict__ Wlo,
                                                const float* __restrict__ bu2,
                                                __hip_bfloat16* __restrict__ M) {
  __shared__ short mbuf[16][132];
  int t = threadIdx.x;
  int lane = t & 63;
  int m = lane & 15;
  int quad = lane >> 4;
  int wid = t >> 6;        // channel quarter: ch base = wid*32

  short8 whi[4][2], wlo[4][2];
#pragma unroll
  for (int kc = 0; kc < 4; kc++)
#pragma unroll
    for (int nt = 0; nt < 2; nt++) {
      int n = wid * 32 + nt * 16 + m;
      whi[kc][nt] = *(const short8*)&Wt[n * 128 + kc * 32 + quad * 8];
      wlo[kc][nt] = *(const short8*)&Wlo[n * 128 + kc * 32 + quad * 8];
    }
  float bias[2];
#pragma unroll
  for (int nt = 0; nt < 2; nt++) bias[nt] = bu2[wid * 32 + nt * 16 + m];

  for (int iter = 0; iter < 13; iter++) {
    int s = iter * 1024 + blockIdx.x;
    if (s < 12500) {
      int node = s * 4 + (m >> 2);
      int attr = m & 3;
      int xn = x[node];
      f32x4 acc[2];
#pragma unroll
      for (int nt = 0; nt < 2; nt++) acc[nt] = (f32x4){0.f, 0.f, 0.f, 0.f};

#pragma unroll
      for (int kc = 0; kc < 4; kc++) {
        int k0 = kc * 32 + quad * 8;
        short8 ahi, alo;
        {
          float u1a[8], bba[8], u2a[8];
          *(float4*)&u1a[0] = *(const float4*)&U1[xn * 128 + k0];
          *(float4*)&u1a[4] = *(const float4*)&U1[xn * 128 + k0 + 4];
          *(float4*)&bba[0] = *(const float4*)&B_[node * 128 + k0];
          *(float4*)&bba[4] = *(const float4*)&B_[node * 128 + k0 + 4];
          *(float4*)&u2a[0] = *(const float4*)&U2c[attr * 128 + k0];
          *(float4*)&u2a[4] = *(const float4*)&U2c[attr * 128 + k0 + 4];
#pragma unroll
          for (int j = 0; j < 8; j++) {
            float hv = u1a[j] + bba[j] + u2a[j];
            hv = hv > 0.f ? hv : 0.f;
            bfbits hi; hi.b = __float2bfloat16(hv);
            float hf = __bfloat162float(hi.b);
            bfbits lo; lo.b = __float2bfloat16(hv - hf);
            ahi[j] = hi.s;
            alo[j] = lo.s;
          }
        }
#pragma unroll
        for (int nt = 0; nt < 2; nt++) {
          acc[nt] = __builtin_amdgcn_mfma_f32_16x16x32_bf16(ahi, whi[kc][nt], acc[nt], 0, 0, 0);
          acc[nt] = __builtin_amdgcn_mfma_f32_16x16x32_bf16(alo, whi[kc][nt], acc[nt], 0, 0, 0);
          acc[nt] = __builtin_amdgcn_mfma_f32_16x16x32_bf16(ahi, wlo[kc][nt], acc[nt], 0, 0, 0);
        }
      }

#pragma unroll
      for (int nt = 0; nt < 2; nt++) {
#pragma unroll
        for (int r = 0; r < 4; r++) {
          float v = acc[nt][r] + bias[nt];
          v = v > 0.f ? v : 0.f;
          bfbits o; o.b = __float2bfloat16(v);
          mbuf[quad * 4 + r][wid * 32 + nt * 16 + m] = o.s;
        }
      }
    }
    __syncthreads();
    if (s < 12500) {
      // coalesced store: 16 rows x 256 B = 256 chunks of 16 B, one per thread
      int row = t >> 4;
      int q = t & 15;
      short8 v = *(const short8*)&mbuf[row][q * 8];
      *(short8*)((short*)M + (s * 16 + row) * 128 + q * 8) = v;
    }
    __syncthreads();
  }
}

// ---------------------------------------------------------------------------
// mol[m] = sum of A rows in [molptr[m], molptr[m+1]) — one wave per mol.
// ---------------------------------------------------------------------------
__global__ void k_molgather(const float* __restrict__ A_, const int* __restrict__ molptr,
                            float* __restrict__ mol) {
  int m = blockIdx.x * 4 + (threadIdx.x >> 6);
  int lane = threadIdx.x & 63;
  int beg = molptr[m], end = molptr[m + 1];
  float ax = 0.f, ay = 0.f;
  int n = beg;
  for (; n + 1 < end; n += 2) {
    float2 v0 = *(const float2*)&A_[n * 128 + lane * 2];
    float2 v1 = *(const float2*)&A_[(n + 1) * 128 + lane * 2];
    ax += v0.x + v1.x;
    ay += v0.y + v1.y;
  }
  if (n < end) {
    float2 v0 = *(const float2*)&A_[n * 128 + lane * 2];
    ax += v0.x;
    ay += v0.y;
  }
  float2 o; o.x = ax; o.y = ay;
  *(float2*)&mol[m * 128 + lane * 2] = o;
}

// ---------------------------------------------------------------------------
// out[m] = relu(mol[m] @ Wr1 + br1) @ Wr2 + br2
// ---------------------------------------------------------------------------
__global__ __launch_bounds__(256) void k_readout(const float* __restrict__ mol,
                                                 const float* __restrict__ Wr1,
                                                 const float* __restrict__ br1,
                                                 const float* __restrict__ Wr2,
                                                 const float* __restrict__ br2,
                                                 float* __restrict__ out) {
  int m = blockIdx.x;
  __shared__ float ms[128];
  __shared__ float red[256];
  int t = threadIdx.x;
  if (t < 128) ms[t] = mol[m * 128 + t];
  __syncthreads();
  float part = 0.f;
#pragma unroll
  for (int jj = 0; jj < 2; jj++) {
    int j = t + jj * 256;
    float acc = br1[j];
#pragma unroll
    for (int k = 0; k < 128; k += 4) {
      float4 m4 = *(const float4*)&ms[k];
      acc += m4.x * Wr1[k * 512 + j] + m4.y * Wr1[(k + 1) * 512 + j] +
             m4.z * Wr1[(k + 2) * 512 + j] + m4.w * Wr1[(k + 3) * 512 + j];
    }
    acc = acc > 0.f ? acc : 0.f;
    part += acc * Wr2[j];
  }
  red[t] = part;
  __syncthreads();
  for (int s = 128; s > 0; s >>= 1) {
    if (t < s) red[t] += red[t + s];
    __syncthreads();
  }
  if (t == 0) out[m] = red[0] + br2[0];
}

// ---------------------------------------------------------------------------
extern "C" void kernel_launch(void* const* d_in, const int* in_sizes, int n_in,
                              void* d_out, int out_size, void* d_ws, size_t ws_size,
                              hipStream_t stream) {
  const int* x        = (const int*)d_in[0];
  const int* eattr    = (const int*)d_in[1];
  const int* eidx     = (const int*)d_in[2];
  const int* batch    = (const int*)d_in[3];
  const float* atom_table = (const float*)d_in[4];
  const float* bond_table = (const float*)d_in[5];
  const float* Wi  = (const float*)d_in[6];
  const float* bi  = (const float*)d_in[7];
  const float* Wu1 = (const float*)d_in[8];
  const float* bu1 = (const float*)d_in[9];
  const float* Wu2 = (const float*)d_in[10];
  const float* bu2 = (const float*)d_in[11];
  const float* Wr1 = (const float*)d_in[12];
  const float* br1 = (const float*)d_in[13];
  const float* Wr2 = (const float*)d_in[14];
  const float* br2 = (const float*)d_in[15];
  float* out = (float*)d_out;

  char* ws = (char*)d_ws;
  __hip_bfloat16* M = (__hip_bfloat16*)(ws);       //  51,200,000 B (bf16)
  short* Wt      = (short*)(ws + 51200000);        //      32,768 B
  short* Wlo     = (short*)(ws + 51232768);        //      32,768 B
  int*   csr0    = (int*)  (ws + 51265536);        //   3,200,000 B
  int*   locinc  = (int*)  (ws + 54465536);        //     200,000 B
  int*   partial = (int*)  (ws + 54665536);        //         256 B
  int*   offs    = (int*)  (ws + 54665792);        //         256 B
  int*   molptr  = (int*)  (ws + 54666048);        //       8,004 B
  float* A       = (float*)(ws + 102400000);       //  25,600,000 B
  float* B       = (float*)(ws + 128000000);       //  25,600,000 B
  int*   csr     = (int*)  (ws + 153600000);       //   3,200,000 B
  int*   rowptr  = (int*)  (ws + 156800000);       //     200,064 B
  float* T1      = (float*)(ws + 157000064);       //      60,928 B
  float* U1      = (float*)(ws + 157060992);       //      60,928 B
  float* T2c     = (float*)(ws + 157121920);       //       2,048 B
  float* U2c     = (float*)(ws + 157123968);       //       2,048 B
  float* TT      = (float*)(ws + 157126016);       //     243,712 B
  float* mol     = (float*)(ws + 157369728);       //   1,024,000 B
  // cnt/cursor alias B: only live before the first k_mm1 write to B.
  int*   cnt     = (int*)B;
  int*   cursor  = (int*)(ws + 128000000 + 204800);

  hipMemsetAsync(cnt, 0, N_NODES * sizeof(int), stream);
  k_tables<<<123, 128, 0, stream>>>(atom_table, bond_table, Wi, bi, Wu1, bu1,
                                    T1, U1, T2c, U2c);
  k_tt<<<476, 128, 0, stream>>>(T1, T2c, TT);
  k_wt<<<128, 128, 0, stream>>>(Wu2, Wt, Wlo);
  k_hist<<<N_EDGES / 256, 256, 0, stream>>>(eidx, cnt);
  k_scanA<<<49, 1024, 0, stream>>>(cnt, locinc, partial);
  k_scanB<<<1, 64, 0, stream>>>(partial, offs);
  k_scanC<<<(N_NODES + 255) / 256, 256, 0, stream>>>(cnt, locinc, offs, rowptr, cursor);
  k_fill<<<N_EDGES / 256, 256, 0, stream>>>(eidx, eattr, x, cursor, csr, csr0);
  k_molptr<<<(NUM_MOL + 256) / 256, 256, 0, stream>>>(batch, molptr);

  k_gather0<<<N_NODES / 4, 256, 0, stream>>>(rowptr, csr0, TT, A);

  for (int p = 0; p < 4; p++) {
    k_mm1<<<(N_NODES + 63) / 64, 256, 0, stream>>>(A, Wu1, B);
    k_mm2<<<1024, 256, 0, stream>>>(B, x, U1, U2c, Wt, Wlo, bu2, M);
    k_gather<<<N_NODES / 4, 256, 0, stream>>>(rowptr, csr, M, A);
  }

  k_molgather<<<NUM_MOL / 4, 256, 0, stream>>>(A, molptr, mol);
  k_readout<<<NUM_MOL, 256, 0, stream>>>(mol, Wr1, br1, Wr2, br2, out);
}

// Round 11
// 889.104 us; speedup vs baseline: 1.0393x; 1.0393x over previous
//
#include <hip/hip_runtime.h>
#include <hip/hip_bf16.h>

#define N_NODES 50000
#define N_EDGES 800000
#define NUM_MOL 2000

typedef __attribute__((ext_vector_type(8))) short short8;
typedef __attribute__((ext_vector_type(4))) float f32x4;

union bfbits { __hip_bfloat16 b; short s; };

// ---------------------------------------------------------------------------
// Type tables.
// ---------------------------------------------------------------------------
__global__ void k_tables(const float* __restrict__ atom_table,
                         const float* __restrict__ bond_table,
                         const float* __restrict__ Wi,
                         const float* __restrict__ bi,
                         const float* __restrict__ Wu1,
                         const float* __restrict__ bu1,
                         float* __restrict__ T1, float* __restrict__ U1,
                         float* __restrict__ T2c, float* __restrict__ U2c) {
  int b = blockIdx.x;
  int c = threadIdx.x;
  if (b < 119) {
    float t = 0.f, u = 0.f;
    for (int k = 0; k < 128; k++) {
      float a = atom_table[b * 128 + k];
      t += a * Wi[k * 128 + c];
      u += a * Wu1[k * 128 + c];
    }
    T1[b * 128 + c] = t;
    U1[b * 128 + c] = u;
  } else {
    int a = b - 119;
    float t = bi[c], u = bu1[c];
    for (int k = 0; k < 64; k++) {
      float bv = bond_table[a * 64 + k];
      t += bv * Wi[(128 + k) * 128 + c];
      u += bv * Wu1[(128 + k) * 128 + c];
    }
    T2c[a * 128 + c] = t;
    U2c[a * 128 + c] = u;
  }
}

// TT[x*4+a, c] = relu(T1[x,c] + T2c[a,c])
__global__ void k_tt(const float* __restrict__ T1, const float* __restrict__ T2c,
                     float* __restrict__ TT) {
  int r = blockIdx.x;   // 0..475
  int c = threadIdx.x;
  float v = T1[(r >> 2) * 128 + c] + T2c[(r & 3) * 128 + c];
  TT[r * 128 + c] = v > 0.f ? v : 0.f;
}

// Wt/Wlo: hi/lo bf16 split of Wu2^T for MFMA B-frags.
__global__ void k_wt(const float* __restrict__ Wu2, short* __restrict__ Wt,
                     short* __restrict__ Wlo) {
  int n = blockIdx.x;
  int k = threadIdx.x;
  float w = Wu2[k * 128 + n];
  bfbits hi; hi.b = __float2bfloat16(w);
  float hf = __bfloat162float(hi.b);
  bfbits lo; lo.b = __float2bfloat16(w - hf);
  Wt[n * 128 + k] = hi.s;
  Wlo[n * 128 + k] = lo.s;
}

// ---------------------------------------------------------------------------
// CSR build: histogram, 3-phase multi-block scan, fill (csr + csr0).
// ---------------------------------------------------------------------------
__global__ void k_hist(const int* __restrict__ eidx, int* __restrict__ cnt) {
  int e = blockIdx.x * 256 + threadIdx.x;
  atomicAdd(&cnt[eidx[N_EDGES + e]], 1);
}

__global__ __launch_bounds__(1024) void k_scanA(const int* __restrict__ cnt,
                                                int* __restrict__ locinc,
                                                int* __restrict__ partial) {
  __shared__ int buf[1024];
  int t = threadIdx.x;
  int i = blockIdx.x * 1024 + t;
  int v = (i < N_NODES) ? cnt[i] : 0;
  buf[t] = v;
  __syncthreads();
  for (int off = 1; off < 1024; off <<= 1) {
    int add = (t >= off) ? buf[t - off] : 0;
    __syncthreads();
    buf[t] += add;
    __syncthreads();
  }
  if (i < N_NODES) locinc[i] = buf[t];
  if (t == 1023) partial[blockIdx.x] = buf[t];
}

__global__ void k_scanB(const int* __restrict__ partial, int* __restrict__ offs) {
  int lane = threadIdx.x;   // 64 threads
  int v = (lane < 49) ? partial[lane] : 0;
  int inc = v;
  for (int d = 1; d < 64; d <<= 1) {
    int u = __shfl_up(inc, d, 64);
    if (lane >= d) inc += u;
  }
  if (lane < 49) offs[lane] = inc - v;   // exclusive
}

__global__ void k_scanC(const int* __restrict__ cnt, const int* __restrict__ locinc,
                        const int* __restrict__ offs,
                        int* __restrict__ rowptr, int* __restrict__ cursor) {
  int i = blockIdx.x * 256 + threadIdx.x;
  if (i < N_NODES) {
    int rp = locinc[i] + offs[i >> 10];
    rowptr[i + 1] = rp;
    cursor[i] = rp - cnt[i];
    if (i == 0) rowptr[0] = 0;
  }
}

__global__ void k_fill(const int* __restrict__ eidx, const int* __restrict__ attr,
                       const int* __restrict__ x,
                       int* __restrict__ cursor, int* __restrict__ csr,
                       int* __restrict__ csr0) {
  int e = blockIdx.x * 256 + threadIdx.x;
  int d = eidx[N_EDGES + e];
  int s = eidx[e];
  int a = attr[e];
  int pos = atomicAdd(&cursor[d], 1);
  csr[pos] = s * 4 + a;
  csr0[pos] = x[s] * 4 + a;
}

// molptr[m] = lower_bound(batch, m)
__global__ void k_molptr(const int* __restrict__ batch, int* __restrict__ molptr) {
  int m = blockIdx.x * 256 + threadIdx.x;
  if (m > NUM_MOL) return;
  int lo = 0, hi = N_NODES;
  while (lo < hi) {
    int mid = (lo + hi) >> 1;
    if (batch[mid] < m) lo = mid + 1; else hi = mid;
  }
  molptr[m] = lo;
}

// ---------------------------------------------------------------------------
// Gather initial messages (r10 layout): 2 rows per VMEM inst, butterfly-32.
// ---------------------------------------------------------------------------
__global__ void k_gather0(const int* __restrict__ rowptr, const int* __restrict__ csr0,
                          const float* __restrict__ TT, float* __restrict__ A_) {
  int n = blockIdx.x * 4 + (threadIdx.x >> 6);
  int lane = threadIdx.x & 63;
  int g = lane >> 5;        // 0..1
  int p = lane & 31;        // channel quad
  int beg = rowptr[n], end = rowptr[n + 1];
  float s0 = 0.f, s1 = 0.f, s2 = 0.f, s3 = 0.f;
  int i = beg;
  for (; i + 3 < end; i += 4) {
    int idxA = csr0[i + g];
    int idxB = csr0[i + 2 + g];
    float4 va = *(const float4*)&TT[idxA * 128 + p * 4];
    float4 vb = *(const float4*)&TT[idxB * 128 + p * 4];
    s0 += va.x + vb.x; s1 += va.y + vb.y;
    s2 += va.z + vb.z; s3 += va.w + vb.w;
  }
  for (; i < end; i += 2) {
    if (i + g < end) {
      int idx = csr0[i + g];
      float4 v = *(const float4*)&TT[idx * 128 + p * 4];
      s0 += v.x; s1 += v.y; s2 += v.z; s3 += v.w;
    }
  }
  s0 += __shfl_xor(s0, 32, 64);
  s1 += __shfl_xor(s1, 32, 64);
  s2 += __shfl_xor(s2, 32, 64);
  s3 += __shfl_xor(s3, 32, 64);
  float2 o;
  o.x = (g == 0) ? s0 : s2;
  o.y = (g == 0) ? s1 : s3;
  *(float2*)&A_[n * 128 + p * 4 + g * 2] = o;
}

// ---------------------------------------------------------------------------
// Gather messages (r10 layout): 4 rows per VMEM inst, butterflies 16/32.
// ---------------------------------------------------------------------------
__global__ void k_gather(const int* __restrict__ rowptr, const int* __restrict__ csr,
                         const __hip_bfloat16* __restrict__ M, float* __restrict__ A_) {
  int n = blockIdx.x * 4 + (threadIdx.x >> 6);
  int lane = threadIdx.x & 63;
  int g = lane >> 4;        // 0..3
  int p = lane & 15;        // channel octet
  int beg = rowptr[n], end = rowptr[n + 1];
  float s[8];
#pragma unroll
  for (int j = 0; j < 8; j++) s[j] = 0.f;
  const short* Ms = (const short*)M;
  int i = beg;
  for (; i + 7 < end; i += 8) {
    int idxA = csr[i + g];
    int idxB = csr[i + 4 + g];
    short8 va = *(const short8*)&Ms[idxA * 128 + p * 8];
    short8 vb = *(const short8*)&Ms[idxB * 128 + p * 8];
#pragma unroll
    for (int j = 0; j < 4; j++) {
      float2 fa = __bfloat1622float2(*(const __hip_bfloat162*)&((const short*)&va)[j * 2]);
      float2 fb = __bfloat1622float2(*(const __hip_bfloat162*)&((const short*)&vb)[j * 2]);
      s[j * 2] += fa.x + fb.x;
      s[j * 2 + 1] += fa.y + fb.y;
    }
  }
  for (; i < end; i += 4) {
    if (i + g < end) {
      int idx = csr[i + g];
      short8 va = *(const short8*)&Ms[idx * 128 + p * 8];
#pragma unroll
      for (int j = 0; j < 4; j++) {
        float2 fa = __bfloat1622float2(*(const __hip_bfloat162*)&((const short*)&va)[j * 2]);
        s[j * 2] += fa.x;
        s[j * 2 + 1] += fa.y;
      }
    }
  }
#pragma unroll
  for (int j = 0; j < 8; j++) s[j] += __shfl_xor(s[j], 16, 64);
#pragma unroll
  for (int j = 0; j < 8; j++) s[j] += __shfl_xor(s[j], 32, 64);
  float2 o;
  o.x = s[g * 2];
  o.y = s[g * 2 + 1];
  *(float2*)&A_[n * 128 + p * 8 + g * 2] = o;
}

// ---------------------------------------------------------------------------
// k_mm1: B = A @ Wu1[192:320,:]  fp32 tiled GEMM.
// ---------------------------------------------------------------------------
__global__ __launch_bounds__(256, 4) void k_mm1(const float* __restrict__ A_,
                                                const float* __restrict__ Wu1,
                                                float* __restrict__ B_) {
  __shared__ float Hs[64][132];
  int t = threadIdx.x;
  int base = blockIdx.x * 64;
#pragma unroll
  for (int j = 0; j < 8; j++) {
    int idx = j * 256 + t;
    int rr = idx >> 5;
    int kq = idx & 31;
    int n = base + rr;
    if (n >= N_NODES) n = N_NODES - 1;
    float4 v = *(const float4*)&A_[n * 128 + kq * 4];
    *(float4*)&Hs[rr][kq * 4] = v;
  }
  __syncthreads();
  int r0 = (t >> 4) * 4;
  int c0 = (t & 15) * 8;
  const float* W = Wu1 + 192 * 128;
  float acc[4][8];
#pragma unroll
  for (int r = 0; r < 4; r++)
#pragma unroll
    for (int j = 0; j < 8; j++) acc[r][j] = 0.f;
#pragma unroll 2
  for (int kq = 0; kq < 32; kq++) {
    const int k = kq * 4;
    float h0[4], h1[4], h2[4], h3[4];
    *(float4*)h0 = *(const float4*)&Hs[r0][k];
    *(float4*)h1 = *(const float4*)&Hs[r0 + 1][k];
    *(float4*)h2 = *(const float4*)&Hs[r0 + 2][k];
    *(float4*)h3 = *(const float4*)&Hs[r0 + 3][k];
#pragma unroll
    for (int i = 0; i < 4; i++) {
      float w[8];
      *(float4*)&w[0] = *(const float4*)&W[(k + i) * 128 + c0];
      *(float4*)&w[4] = *(const float4*)&W[(k + i) * 128 + c0 + 4];
      float hv[4] = {h0[i], h1[i], h2[i], h3[i]};
#pragma unroll
      for (int r = 0; r < 4; r++)
#pragma unroll
        for (int j = 0; j < 8; j++) acc[r][j] += hv[r] * w[j];
    }
  }
#pragma unroll
  for (int r = 0; r < 4; r++) {
    int n = base + r0 + r;
    if (n < N_NODES) {
      float4 o0, o1;
      o0.x = acc[r][0]; o0.y = acc[r][1]; o0.z = acc[r][2]; o0.w = acc[r][3];
      o1.x = acc[r][4]; o1.y = acc[r][5]; o1.z = acc[r][6]; o1.w = acc[r][7];
      *(float4*)&B_[n * 128 + c0] = o0;
      *(float4*)&B_[n * 128 + c0 + 4] = o1;
    }
  }
}

// ---------------------------------------------------------------------------
// k_mm2 v6: r9-v4 data layout (2 waves per slab, 64 ch each, whi+wlo in
// VGPRs) but block = 128 threads = ONE slab. No cross-slab barrier
// coupling; grid 2048 small blocks give the scheduler freedom.
//   D = ahi@Whi + alo@Whi + ahi@Wlo   (H exact via hi/lo split).
// ---------------------------------------------------------------------------
__global__ __launch_bounds__(128) void k_mm2(const float* __restrict__ B_,
                                             const int* __restrict__ x,
                                             const float* __restrict__ U1,
                                             const float* __restrict__ U2c,
                                             const short* __restrict__ Wt,
                                             const short* __restrict__ Wlo,
                                             const float* __restrict__ bu2,
                                             __hip_bfloat16* __restrict__ M) {
  __shared__ short mbuf[16][132];
  int t = threadIdx.x;
  int lane = t & 63;
  int m = lane & 15;
  int quad = lane >> 4;
  int h = t >> 6;          // channel half (0: ch 0-63, 1: ch 64-127)

  // per-wave weights in VGPRs: 4 kc x 4 nt, hi + lo = 128 VGPRs
  short8 whi[4][4], wlo[4][4];
#pragma unroll
  for (int kc = 0; kc < 4; kc++)
#pragma unroll
    for (int nt = 0; nt < 4; nt++) {
      int n = h * 64 + nt * 16 + m;
      whi[kc][nt] = *(const short8*)&Wt[n * 128 + kc * 32 + quad * 8];
      wlo[kc][nt] = *(const short8*)&Wlo[n * 128 + kc * 32 + quad * 8];
    }
  float bias[4];
#pragma unroll
  for (int nt = 0; nt < 4; nt++) bias[nt] = bu2[h * 64 + nt * 16 + m];

  for (int iter = 0; iter < 7; iter++) {
    int s = iter * 2048 + blockIdx.x;
    if (s < 12500) {
      int node = s * 4 + (m >> 2);
      int attr = m & 3;
      int xn = x[node];
      f32x4 acc[4];
#pragma unroll
      for (int nt = 0; nt < 4; nt++) acc[nt] = (f32x4){0.f, 0.f, 0.f, 0.f};

#pragma unroll
      for (int kc = 0; kc < 4; kc++) {
        int k0 = kc * 32 + quad * 8;
        short8 ahi, alo;
        {
          float u1a[8], bba[8], u2a[8];
          *(float4*)&u1a[0] = *(const float4*)&U1[xn * 128 + k0];
          *(float4*)&u1a[4] = *(const float4*)&U1[xn * 128 + k0 + 4];
          *(float4*)&bba[0] = *(const float4*)&B_[node * 128 + k0];
          *(float4*)&bba[4] = *(const float4*)&B_[node * 128 + k0 + 4];
          *(float4*)&u2a[0] = *(const float4*)&U2c[attr * 128 + k0];
          *(float4*)&u2a[4] = *(const float4*)&U2c[attr * 128 + k0 + 4];
#pragma unroll
          for (int j = 0; j < 8; j++) {
            float hv = u1a[j] + bba[j] + u2a[j];
            hv = hv > 0.f ? hv : 0.f;
            bfbits hi; hi.b = __float2bfloat16(hv);
            float hf = __bfloat162float(hi.b);
            bfbits lo; lo.b = __float2bfloat16(hv - hf);
            ahi[j] = hi.s;
            alo[j] = lo.s;
          }
        }
#pragma unroll
        for (int nt = 0; nt < 4; nt++) {
          acc[nt] = __builtin_amdgcn_mfma_f32_16x16x32_bf16(ahi, whi[kc][nt], acc[nt], 0, 0, 0);
          acc[nt] = __builtin_amdgcn_mfma_f32_16x16x32_bf16(alo, whi[kc][nt], acc[nt], 0, 0, 0);
          acc[nt] = __builtin_amdgcn_mfma_f32_16x16x32_bf16(ahi, wlo[kc][nt], acc[nt], 0, 0, 0);
        }
      }

#pragma unroll
      for (int nt = 0; nt < 4; nt++) {
#pragma unroll
        for (int r = 0; r < 4; r++) {
          float v = acc[nt][r] + bias[nt];
          v = v > 0.f ? v : 0.f;
          bfbits o; o.b = __float2bfloat16(v);
          mbuf[quad * 4 + r][h * 64 + nt * 16 + m] = o.s;
        }
      }
    }
    __syncthreads();
    if (s < 12500) {
      // coalesced store: 16 rows x 256 B = 256 chunks of 16 B, 2 per thread
#pragma unroll
      for (int p = 0; p < 2; p++) {
        int chunk = p * 128 + t;
        int row = chunk >> 4;
        int q = chunk & 15;
        short8 v = *(const short8*)&mbuf[row][q * 8];
        *(short8*)((short*)M + (s * 16 + row) * 128 + q * 8) = v;
      }
    }
    __syncthreads();
  }
}

// ---------------------------------------------------------------------------
// mol[m] = sum of A rows in [molptr[m], molptr[m+1]) — one wave per mol.
// ---------------------------------------------------------------------------
__global__ void k_molgather(const float* __restrict__ A_, const int* __restrict__ molptr,
                            float* __restrict__ mol) {
  int m = blockIdx.x * 4 + (threadIdx.x >> 6);
  int lane = threadIdx.x & 63;
  int beg = molptr[m], end = molptr[m + 1];
  float ax = 0.f, ay = 0.f;
  int n = beg;
  for (; n + 1 < end; n += 2) {
    float2 v0 = *(const float2*)&A_[n * 128 + lane * 2];
    float2 v1 = *(const float2*)&A_[(n + 1) * 128 + lane * 2];
    ax += v0.x + v1.x;
    ay += v0.y + v1.y;
  }
  if (n < end) {
    float2 v0 = *(const float2*)&A_[n * 128 + lane * 2];
    ax += v0.x;
    ay += v0.y;
  }
  float2 o; o.x = ax; o.y = ay;
  *(float2*)&mol[m * 128 + lane * 2] = o;
}

// ---------------------------------------------------------------------------
// out[m] = relu(mol[m] @ Wr1 + br1) @ Wr2 + br2
// ---------------------------------------------------------------------------
__global__ __launch_bounds__(256) void k_readout(const float* __restrict__ mol,
                                                 const float* __restrict__ Wr1,
                                                 const float* __restrict__ br1,
                                                 const float* __restrict__ Wr2,
                                                 const float* __restrict__ br2,
                                                 float* __restrict__ out) {
  int m = blockIdx.x;
  __shared__ float ms[128];
  __shared__ float red[256];
  int t = threadIdx.x;
  if (t < 128) ms[t] = mol[m * 128 + t];
  __syncthreads();
  float part = 0.f;
#pragma unroll
  for (int jj = 0; jj < 2; jj++) {
    int j = t + jj * 256;
    float acc = br1[j];
#pragma unroll
    for (int k = 0; k < 128; k += 4) {
      float4 m4 = *(const float4*)&ms[k];
      acc += m4.x * Wr1[k * 512 + j] + m4.y * Wr1[(k + 1) * 512 + j] +
             m4.z * Wr1[(k + 2) * 512 + j] + m4.w * Wr1[(k + 3) * 512 + j];
    }
    acc = acc > 0.f ? acc : 0.f;
    part += acc * Wr2[j];
  }
  red[t] = part;
  __syncthreads();
  for (int s = 128; s > 0; s >>= 1) {
    if (t < s) red[t] += red[t + s];
    __syncthreads();
  }
  if (t == 0) out[m] = red[0] + br2[0];
}

// ---------------------------------------------------------------------------
extern "C" void kernel_launch(void* const* d_in, const int* in_sizes, int n_in,
                              void* d_out, int out_size, void* d_ws, size_t ws_size,
                              hipStream_t stream) {
  const int* x        = (const int*)d_in[0];
  const int* eattr    = (const int*)d_in[1];
  const int* eidx     = (const int*)d_in[2];
  const int* batch    = (const int*)d_in[3];
  const float* atom_table = (const float*)d_in[4];
  const float* bond_table = (const float*)d_in[5];
  const float* Wi  = (const float*)d_in[6];
  const float* bi  = (const float*)d_in[7];
  const float* Wu1 = (const float*)d_in[8];
  const float* bu1 = (const float*)d_in[9];
  const float* Wu2 = (const float*)d_in[10];
  const float* bu2 = (const float*)d_in[11];
  const float* Wr1 = (const float*)d_in[12];
  const float* br1 = (const float*)d_in[13];
  const float* Wr2 = (const float*)d_in[14];
  const float* br2 = (const float*)d_in[15];
  float* out = (float*)d_out;

  char* ws = (char*)d_ws;
  __hip_bfloat16* M = (__hip_bfloat16*)(ws);       //  51,200,000 B (bf16)
  short* Wt      = (short*)(ws + 51200000);        //      32,768 B
  short* Wlo     = (short*)(ws + 51232768);        //      32,768 B
  int*   csr0    = (int*)  (ws + 51265536);        //   3,200,000 B
  int*   locinc  = (int*)  (ws + 54465536);        //     200,000 B
  int*   partial = (int*)  (ws + 54665536);        //         256 B
  int*   offs    = (int*)  (ws + 54665792);        //         256 B
  int*   molptr  = (int*)  (ws + 54666048);        //       8,004 B
  float* A       = (float*)(ws + 102400000);       //  25,600,000 B
  float* B       = (float*)(ws + 128000000);       //  25,600,000 B
  int*   csr     = (int*)  (ws + 153600000);       //   3,200,000 B
  int*   rowptr  = (int*)  (ws + 156800000);       //     200,064 B
  float* T1      = (float*)(ws + 157000064);       //      60,928 B
  float* U1      = (float*)(ws + 157060992);       //      60,928 B
  float* T2c     = (float*)(ws + 157121920);       //       2,048 B
  float* U2c     = (float*)(ws + 157123968);       //       2,048 B
  float* TT      = (float*)(ws + 157126016);       //     243,712 B
  float* mol     = (float*)(ws + 157369728);       //   1,024,000 B
  // cnt/cursor alias B: only live before the first k_mm1 write to B.
  int*   cnt     = (int*)B;
  int*   cursor  = (int*)(ws + 128000000 + 204800);

  hipMemsetAsync(cnt, 0, N_NODES * sizeof(int), stream);
  k_tables<<<123, 128, 0, stream>>>(atom_table, bond_table, Wi, bi, Wu1, bu1,
                                    T1, U1, T2c, U2c);
  k_tt<<<476, 128, 0, stream>>>(T1, T2c, TT);
  k_wt<<<128, 128, 0, stream>>>(Wu2, Wt, Wlo);
  k_hist<<<N_EDGES / 256, 256, 0, stream>>>(eidx, cnt);
  k_scanA<<<49, 1024, 0, stream>>>(cnt, locinc, partial);
  k_scanB<<<1, 64, 0, stream>>>(partial, offs);
  k_scanC<<<(N_NODES + 255) / 256, 256, 0, stream>>>(cnt, locinc, offs, rowptr, cursor);
  k_fill<<<N_EDGES / 256, 256, 0, stream>>>(eidx, eattr, x, cursor, csr, csr0);
  k_molptr<<<(NUM_MOL + 256) / 256, 256, 0, stream>>>(batch, molptr);

  k_gather0<<<N_NODES / 4, 256, 0, stream>>>(rowptr, csr0, TT, A);

  for (int p = 0; p < 4; p++) {
    k_mm1<<<(N_NODES + 63) / 64, 256, 0, stream>>>(A, Wu1, B);
    k_mm2<<<2048, 128, 0, stream>>>(B, x, U1, U2c, Wt, Wlo, bu2, M);
    k_gather<<<N_NODES / 4, 256, 0, stream>>>(rowptr, csr, M, A);
  }

  k_molgather<<<NUM_MOL / 4, 256, 0, stream>>>(A, molptr, mol);
  k_readout<<<NUM_MOL, 256, 0, stream>>>(mol, Wr1, br1, Wr2, br2, out);
}

// Round 12
// 825.106 us; speedup vs baseline: 1.1199x; 1.0776x over previous
//
#include <hip/hip_runtime.h>
#include <hip/hip_bf16.h>

#define N_NODES 50000
#define N_EDGES 800000
#define NUM_MOL 2000

typedef __attribute__((ext_vector_type(8))) short short8;
typedef __attribute__((ext_vector_type(4))) float f32x4;

union bfbits { __hip_bfloat16 b; short s; };

// ---------------------------------------------------------------------------
// Type tables.
// ---------------------------------------------------------------------------
__global__ void k_tables(const float* __restrict__ atom_table,
                         const float* __restrict__ bond_table,
                         const float* __restrict__ Wi,
                         const float* __restrict__ bi,
                         const float* __restrict__ Wu1,
                         const float* __restrict__ bu1,
                         float* __restrict__ T1, float* __restrict__ U1,
                         float* __restrict__ T2c, float* __restrict__ U2c) {
  int b = blockIdx.x;
  int c = threadIdx.x;
  if (b < 119) {
    float t = 0.f, u = 0.f;
    for (int k = 0; k < 128; k++) {
      float a = atom_table[b * 128 + k];
      t += a * Wi[k * 128 + c];
      u += a * Wu1[k * 128 + c];
    }
    T1[b * 128 + c] = t;
    U1[b * 128 + c] = u;
  } else {
    int a = b - 119;
    float t = bi[c], u = bu1[c];
    for (int k = 0; k < 64; k++) {
      float bv = bond_table[a * 64 + k];
      t += bv * Wi[(128 + k) * 128 + c];
      u += bv * Wu1[(128 + k) * 128 + c];
    }
    T2c[a * 128 + c] = t;
    U2c[a * 128 + c] = u;
  }
}

// TT[x*4+a, c] = relu(T1[x,c] + T2c[a,c])
__global__ void k_tt(const float* __restrict__ T1, const float* __restrict__ T2c,
                     float* __restrict__ TT) {
  int r = blockIdx.x;   // 0..475
  int c = threadIdx.x;
  float v = T1[(r >> 2) * 128 + c] + T2c[(r & 3) * 128 + c];
  TT[r * 128 + c] = v > 0.f ? v : 0.f;
}

// Wt/Wlo: hi/lo bf16 split of Wu2^T for MFMA B-frags.
__global__ void k_wt(const float* __restrict__ Wu2, short* __restrict__ Wt,
                     short* __restrict__ Wlo) {
  int n = blockIdx.x;
  int k = threadIdx.x;
  float w = Wu2[k * 128 + n];
  bfbits hi; hi.b = __float2bfloat16(w);
  float hf = __bfloat162float(hi.b);
  bfbits lo; lo.b = __float2bfloat16(w - hf);
  Wt[n * 128 + k] = hi.s;
  Wlo[n * 128 + k] = lo.s;
}

// D_[n] = U1[x[n]]  -- pass-invariant, kills the x->U1 chain in mm2.
__global__ void k_u1x(const int* __restrict__ x, const float* __restrict__ U1,
                      float* __restrict__ D_) {
  int n = blockIdx.x * 4 + (threadIdx.x >> 6);
  int lane = threadIdx.x & 63;
  int xn = x[n];
  float2 v = *(const float2*)&U1[xn * 128 + lane * 2];
  *(float2*)&D_[n * 128 + lane * 2] = v;
}

// ---------------------------------------------------------------------------
// CSR build: histogram, 3-phase multi-block scan, fill (csr + csr0).
// ---------------------------------------------------------------------------
__global__ void k_hist(const int* __restrict__ eidx, int* __restrict__ cnt) {
  int e = blockIdx.x * 256 + threadIdx.x;
  atomicAdd(&cnt[eidx[N_EDGES + e]], 1);
}

__global__ __launch_bounds__(1024) void k_scanA(const int* __restrict__ cnt,
                                                int* __restrict__ locinc,
                                                int* __restrict__ partial) {
  __shared__ int buf[1024];
  int t = threadIdx.x;
  int i = blockIdx.x * 1024 + t;
  int v = (i < N_NODES) ? cnt[i] : 0;
  buf[t] = v;
  __syncthreads();
  for (int off = 1; off < 1024; off <<= 1) {
    int add = (t >= off) ? buf[t - off] : 0;
    __syncthreads();
    buf[t] += add;
    __syncthreads();
  }
  if (i < N_NODES) locinc[i] = buf[t];
  if (t == 1023) partial[blockIdx.x] = buf[t];
}

__global__ void k_scanB(const int* __restrict__ partial, int* __restrict__ offs) {
  int lane = threadIdx.x;   // 64 threads
  int v = (lane < 49) ? partial[lane] : 0;
  int inc = v;
  for (int d = 1; d < 64; d <<= 1) {
    int u = __shfl_up(inc, d, 64);
    if (lane >= d) inc += u;
  }
  if (lane < 49) offs[lane] = inc - v;   // exclusive
}

__global__ void k_scanC(const int* __restrict__ cnt, const int* __restrict__ locinc,
                        const int* __restrict__ offs,
                        int* __restrict__ rowptr, int* __restrict__ cursor) {
  int i = blockIdx.x * 256 + threadIdx.x;
  if (i < N_NODES) {
    int rp = locinc[i] + offs[i >> 10];
    rowptr[i + 1] = rp;
    cursor[i] = rp - cnt[i];
    if (i == 0) rowptr[0] = 0;
  }
}

__global__ void k_fill(const int* __restrict__ eidx, const int* __restrict__ attr,
                       const int* __restrict__ x,
                       int* __restrict__ cursor, int* __restrict__ csr,
                       int* __restrict__ csr0) {
  int e = blockIdx.x * 256 + threadIdx.x;
  int d = eidx[N_EDGES + e];
  int s = eidx[e];
  int a = attr[e];
  int pos = atomicAdd(&cursor[d], 1);
  csr[pos] = s * 4 + a;
  csr0[pos] = x[s] * 4 + a;
}

// molptr[m] = lower_bound(batch, m)
__global__ void k_molptr(const int* __restrict__ batch, int* __restrict__ molptr) {
  int m = blockIdx.x * 256 + threadIdx.x;
  if (m > NUM_MOL) return;
  int lo = 0, hi = N_NODES;
  while (lo < hi) {
    int mid = (lo + hi) >> 1;
    if (batch[mid] < m) lo = mid + 1; else hi = mid;
  }
  molptr[m] = lo;
}

// ---------------------------------------------------------------------------
// Gather initial messages: 2 rows per VMEM inst, butterfly-32.
// ---------------------------------------------------------------------------
__global__ void k_gather0(const int* __restrict__ rowptr, const int* __restrict__ csr0,
                          const float* __restrict__ TT, float* __restrict__ A_) {
  int n = blockIdx.x * 4 + (threadIdx.x >> 6);
  int lane = threadIdx.x & 63;
  int g = lane >> 5;        // 0..1
  int p = lane & 31;        // channel quad
  int beg = rowptr[n], end = rowptr[n + 1];
  float s0 = 0.f, s1 = 0.f, s2 = 0.f, s3 = 0.f;
  int i = beg;
  for (; i + 3 < end; i += 4) {
    int idxA = csr0[i + g];
    int idxB = csr0[i + 2 + g];
    float4 va = *(const float4*)&TT[idxA * 128 + p * 4];
    float4 vb = *(const float4*)&TT[idxB * 128 + p * 4];
    s0 += va.x + vb.x; s1 += va.y + vb.y;
    s2 += va.z + vb.z; s3 += va.w + vb.w;
  }
  for (; i < end; i += 2) {
    if (i + g < end) {
      int idx = csr0[i + g];
      float4 v = *(const float4*)&TT[idx * 128 + p * 4];
      s0 += v.x; s1 += v.y; s2 += v.z; s3 += v.w;
    }
  }
  s0 += __shfl_xor(s0, 32, 64);
  s1 += __shfl_xor(s1, 32, 64);
  s2 += __shfl_xor(s2, 32, 64);
  s3 += __shfl_xor(s3, 32, 64);
  float2 o;
  o.x = (g == 0) ? s0 : s2;
  o.y = (g == 0) ? s1 : s3;
  *(float2*)&A_[n * 128 + p * 4 + g * 2] = o;
}

// ---------------------------------------------------------------------------
// Gather messages: 4 rows per VMEM inst, butterflies 16/32.
// ---------------------------------------------------------------------------
__global__ void k_gather(const int* __restrict__ rowptr, const int* __restrict__ csr,
                         const __hip_bfloat16* __restrict__ M, float* __restrict__ A_) {
  int n = blockIdx.x * 4 + (threadIdx.x >> 6);
  int lane = threadIdx.x & 63;
  int g = lane >> 4;        // 0..3
  int p = lane & 15;        // channel octet
  int beg = rowptr[n], end = rowptr[n + 1];
  float s[8];
#pragma unroll
  for (int j = 0; j < 8; j++) s[j] = 0.f;
  const short* Ms = (const short*)M;
  int i = beg;
  for (; i + 7 < end; i += 8) {
    int idxA = csr[i + g];
    int idxB = csr[i + 4 + g];
    short8 va = *(const short8*)&Ms[idxA * 128 + p * 8];
    short8 vb = *(const short8*)&Ms[idxB * 128 + p * 8];
#pragma unroll
    for (int j = 0; j < 4; j++) {
      float2 fa = __bfloat1622float2(*(const __hip_bfloat162*)&((const short*)&va)[j * 2]);
      float2 fb = __bfloat1622float2(*(const __hip_bfloat162*)&((const short*)&vb)[j * 2]);
      s[j * 2] += fa.x + fb.x;
      s[j * 2 + 1] += fa.y + fb.y;
    }
  }
  for (; i < end; i += 4) {
    if (i + g < end) {
      int idx = csr[i + g];
      short8 va = *(const short8*)&Ms[idx * 128 + p * 8];
#pragma unroll
      for (int j = 0; j < 4; j++) {
        float2 fa = __bfloat1622float2(*(const __hip_bfloat162*)&((const short*)&va)[j * 2]);
        s[j * 2] += fa.x;
        s[j * 2 + 1] += fa.y;
      }
    }
  }
#pragma unroll
  for (int j = 0; j < 8; j++) s[j] += __shfl_xor(s[j], 16, 64);
#pragma unroll
  for (int j = 0; j < 8; j++) s[j] += __shfl_xor(s[j], 32, 64);
  float2 o;
  o.x = s[g * 2];
  o.y = s[g * 2 + 1];
  *(float2*)&A_[n * 128 + p * 8 + g * 2] = o;
}

// ---------------------------------------------------------------------------
// k_mm1: B2 = A @ Wu1[192:320,:] + D   (D = U1[x[n]], folded in epilogue).
// ---------------------------------------------------------------------------
__global__ __launch_bounds__(256, 4) void k_mm1(const float* __restrict__ A_,
                                                const float* __restrict__ Wu1,
                                                const float* __restrict__ D_,
                                                float* __restrict__ B2_) {
  __shared__ float Hs[64][132];
  int t = threadIdx.x;
  int base = blockIdx.x * 64;
#pragma unroll
  for (int j = 0; j < 8; j++) {
    int idx = j * 256 + t;
    int rr = idx >> 5;
    int kq = idx & 31;
    int n = base + rr;
    if (n >= N_NODES) n = N_NODES - 1;
    float4 v = *(const float4*)&A_[n * 128 + kq * 4];
    *(float4*)&Hs[rr][kq * 4] = v;
  }
  __syncthreads();
  int r0 = (t >> 4) * 4;
  int c0 = (t & 15) * 8;
  const float* W = Wu1 + 192 * 128;
  float acc[4][8];
#pragma unroll
  for (int r = 0; r < 4; r++)
#pragma unroll
    for (int j = 0; j < 8; j++) acc[r][j] = 0.f;
#pragma unroll 2
  for (int kq = 0; kq < 32; kq++) {
    const int k = kq * 4;
    float h0[4], h1[4], h2[4], h3[4];
    *(float4*)h0 = *(const float4*)&Hs[r0][k];
    *(float4*)h1 = *(const float4*)&Hs[r0 + 1][k];
    *(float4*)h2 = *(const float4*)&Hs[r0 + 2][k];
    *(float4*)h3 = *(const float4*)&Hs[r0 + 3][k];
#pragma unroll
    for (int i = 0; i < 4; i++) {
      float w[8];
      *(float4*)&w[0] = *(const float4*)&W[(k + i) * 128 + c0];
      *(float4*)&w[4] = *(const float4*)&W[(k + i) * 128 + c0 + 4];
      float hv[4] = {h0[i], h1[i], h2[i], h3[i]};
#pragma unroll
      for (int r = 0; r < 4; r++)
#pragma unroll
        for (int j = 0; j < 8; j++) acc[r][j] += hv[r] * w[j];
    }
  }
#pragma unroll
  for (int r = 0; r < 4; r++) {
    int n = base + r0 + r;
    if (n < N_NODES) {
      float4 d0 = *(const float4*)&D_[n * 128 + c0];
      float4 d1 = *(const float4*)&D_[n * 128 + c0 + 4];
      float4 o0, o1;
      o0.x = acc[r][0] + d0.x; o0.y = acc[r][1] + d0.y;
      o0.z = acc[r][2] + d0.z; o0.w = acc[r][3] + d0.w;
      o1.x = acc[r][4] + d1.x; o1.y = acc[r][5] + d1.y;
      o1.z = acc[r][6] + d1.z; o1.w = acc[r][7] + d1.w;
      *(float4*)&B2_[n * 128 + c0] = o0;
      *(float4*)&B2_[n * 128 + c0 + 4] = o1;
    }
  }
}

// ---------------------------------------------------------------------------
// k_mm2 v7: r9-v4 shape (2 waves/slab, 64 ch each, whi+wlo in VGPRs,
// 256-thread block = 2 slabs, grid 1024) — but per-slab loads are now ONLY
// B2_ (direct) + U2c (L1-hot). No x, no U1, no dependent address chain.
//   H = relu(B2[node] + U2c[attr]);  D = ahi@Whi + alo@Whi + ahi@Wlo.
// ---------------------------------------------------------------------------
__global__ __launch_bounds__(256, 2) void k_mm2(const float* __restrict__ B2_,
                                                const float* __restrict__ U2c,
                                                const short* __restrict__ Wt,
                                                const short* __restrict__ Wlo,
                                                const float* __restrict__ bu2,
                                                __hip_bfloat16* __restrict__ M) {
  __shared__ short mbuf[2][16][132];
  int t = threadIdx.x;
  int lane = t & 63;
  int m = lane & 15;
  int quad = lane >> 4;
  int wid = t >> 6;
  int pairid = wid >> 1;
  int h = wid & 1;

  short8 whi[4][4], wlo[4][4];
#pragma unroll
  for (int kc = 0; kc < 4; kc++)
#pragma unroll
    for (int nt = 0; nt < 4; nt++) {
      int n = h * 64 + nt * 16 + m;
      whi[kc][nt] = *(const short8*)&Wt[n * 128 + kc * 32 + quad * 8];
      wlo[kc][nt] = *(const short8*)&Wlo[n * 128 + kc * 32 + quad * 8];
    }
  float bias[4];
#pragma unroll
  for (int nt = 0; nt < 4; nt++) bias[nt] = bu2[h * 64 + nt * 16 + m];

  for (int iter = 0; iter < 7; iter++) {
    int s = iter * 2048 + blockIdx.x * 2 + pairid;
    if (s < 12500) {
      int node = s * 4 + (m >> 2);
      int attr = m & 3;
      f32x4 acc[4];
#pragma unroll
      for (int nt = 0; nt < 4; nt++) acc[nt] = (f32x4){0.f, 0.f, 0.f, 0.f};

#pragma unroll
      for (int kc = 0; kc < 4; kc++) {
        int k0 = kc * 32 + quad * 8;
        short8 ahi, alo;
        {
          float bba[8], u2a[8];
          *(float4*)&bba[0] = *(const float4*)&B2_[node * 128 + k0];
          *(float4*)&bba[4] = *(const float4*)&B2_[node * 128 + k0 + 4];
          *(float4*)&u2a[0] = *(const float4*)&U2c[attr * 128 + k0];
          *(float4*)&u2a[4] = *(const float4*)&U2c[attr * 128 + k0 + 4];
#pragma unroll
          for (int j = 0; j < 8; j++) {
            float hv = bba[j] + u2a[j];
            hv = hv > 0.f ? hv : 0.f;
            bfbits hi; hi.b = __float2bfloat16(hv);
            float hf = __bfloat162float(hi.b);
            bfbits lo; lo.b = __float2bfloat16(hv - hf);
            ahi[j] = hi.s;
            alo[j] = lo.s;
          }
        }
#pragma unroll
        for (int nt = 0; nt < 4; nt++) {
          acc[nt] = __builtin_amdgcn_mfma_f32_16x16x32_bf16(ahi, whi[kc][nt], acc[nt], 0, 0, 0);
          acc[nt] = __builtin_amdgcn_mfma_f32_16x16x32_bf16(alo, whi[kc][nt], acc[nt], 0, 0, 0);
          acc[nt] = __builtin_amdgcn_mfma_f32_16x16x32_bf16(ahi, wlo[kc][nt], acc[nt], 0, 0, 0);
        }
      }

#pragma unroll
      for (int nt = 0; nt < 4; nt++) {
#pragma unroll
        for (int r = 0; r < 4; r++) {
          float v = acc[nt][r] + bias[nt];
          v = v > 0.f ? v : 0.f;
          bfbits o; o.b = __float2bfloat16(v);
          mbuf[pairid][quad * 4 + r][h * 64 + nt * 16 + m] = o.s;
        }
      }
    }
    __syncthreads();
#pragma unroll
    for (int p = 0; p < 2; p++) {
      int chunk = p * 256 + t;
      int row = chunk >> 4;
      int sg = iter * 2048 + blockIdx.x * 2 + (row >> 4);
      if (sg < 12500) {
        int r = row & 15;
        short8 v = *(const short8*)&mbuf[row >> 4][r][(chunk & 15) * 8];
        *(short8*)((short*)M + (sg * 16 + r) * 128 + (chunk & 15) * 8) = v;
      }
    }
    __syncthreads();
  }
}

// ---------------------------------------------------------------------------
// mol[m] = sum of A rows in [molptr[m], molptr[m+1]) — one wave per mol.
// ---------------------------------------------------------------------------
__global__ void k_molgather(const float* __restrict__ A_, const int* __restrict__ molptr,
                            float* __restrict__ mol) {
  int m = blockIdx.x * 4 + (threadIdx.x >> 6);
  int lane = threadIdx.x & 63;
  int beg = molptr[m], end = molptr[m + 1];
  float ax = 0.f, ay = 0.f;
  int n = beg;
  for (; n + 1 < end; n += 2) {
    float2 v0 = *(const float2*)&A_[n * 128 + lane * 2];
    float2 v1 = *(const float2*)&A_[(n + 1) * 128 + lane * 2];
    ax += v0.x + v1.x;
    ay += v0.y + v1.y;
  }
  if (n < end) {
    float2 v0 = *(const float2*)&A_[n * 128 + lane * 2];
    ax += v0.x;
    ay += v0.y;
  }
  float2 o; o.x = ax; o.y = ay;
  *(float2*)&mol[m * 128 + lane * 2] = o;
}

// ---------------------------------------------------------------------------
// out[m] = relu(mol[m] @ Wr1 + br1) @ Wr2 + br2
// ---------------------------------------------------------------------------
__global__ __launch_bounds__(256) void k_readout(const float* __restrict__ mol,
                                                 const float* __restrict__ Wr1,
                                                 const float* __restrict__ br1,
                                                 const float* __restrict__ Wr2,
                                                 const float* __restrict__ br2,
                                                 float* __restrict__ out) {
  int m = blockIdx.x;
  __shared__ float ms[128];
  __shared__ float red[256];
  int t = threadIdx.x;
  if (t < 128) ms[t] = mol[m * 128 + t];
  __syncthreads();
  float part = 0.f;
#pragma unroll
  for (int jj = 0; jj < 2; jj++) {
    int j = t + jj * 256;
    float acc = br1[j];
#pragma unroll
    for (int k = 0; k < 128; k += 4) {
      float4 m4 = *(const float4*)&ms[k];
      acc += m4.x * Wr1[k * 512 + j] + m4.y * Wr1[(k + 1) * 512 + j] +
             m4.z * Wr1[(k + 2) * 512 + j] + m4.w * Wr1[(k + 3) * 512 + j];
    }
    acc = acc > 0.f ? acc : 0.f;
    part += acc * Wr2[j];
  }
  red[t] = part;
  __syncthreads();
  for (int s = 128; s > 0; s >>= 1) {
    if (t < s) red[t] += red[t + s];
    __syncthreads();
  }
  if (t == 0) out[m] = red[0] + br2[0];
}

// ---------------------------------------------------------------------------
extern "C" void kernel_launch(void* const* d_in, const int* in_sizes, int n_in,
                              void* d_out, int out_size, void* d_ws, size_t ws_size,
                              hipStream_t stream) {
  const int* x        = (const int*)d_in[0];
  const int* eattr    = (const int*)d_in[1];
  const int* eidx     = (const int*)d_in[2];
  const int* batch    = (const int*)d_in[3];
  const float* atom_table = (const float*)d_in[4];
  const float* bond_table = (const float*)d_in[5];
  const float* Wi  = (const float*)d_in[6];
  const float* bi  = (const float*)d_in[7];
  const float* Wu1 = (const float*)d_in[8];
  const float* bu1 = (const float*)d_in[9];
  const float* Wu2 = (const float*)d_in[10];
  const float* bu2 = (const float*)d_in[11];
  const float* Wr1 = (const float*)d_in[12];
  const float* br1 = (const float*)d_in[13];
  const float* Wr2 = (const float*)d_in[14];
  const float* br2 = (const float*)d_in[15];
  float* out = (float*)d_out;

  char* ws = (char*)d_ws;
  __hip_bfloat16* M = (__hip_bfloat16*)(ws);       //  51,200,000 B (bf16)
  short* Wt      = (short*)(ws + 51200000);        //      32,768 B
  short* Wlo     = (short*)(ws + 51232768);        //      32,768 B
  int*   csr0    = (int*)  (ws + 51265536);        //   3,200,000 B
  int*   locinc  = (int*)  (ws + 54465536);        //     200,000 B
  int*   partial = (int*)  (ws + 54665536);        //         256 B
  int*   offs    = (int*)  (ws + 54665792);        //         256 B
  int*   molptr  = (int*)  (ws + 54666048);        //       8,004 B
  float* D       = (float*)(ws + 60000000);        //  25,600,000 B (U1[x[n]])
  float* A       = (float*)(ws + 102400000);       //  25,600,000 B
  float* B2      = (float*)(ws + 128000000);       //  25,600,000 B
  int*   csr     = (int*)  (ws + 153600000);       //   3,200,000 B
  int*   rowptr  = (int*)  (ws + 156800000);       //     200,064 B
  float* T1      = (float*)(ws + 157000064);       //      60,928 B
  float* U1      = (float*)(ws + 157060992);       //      60,928 B
  float* T2c     = (float*)(ws + 157121920);       //       2,048 B
  float* U2c     = (float*)(ws + 157123968);       //       2,048 B
  float* TT      = (float*)(ws + 157126016);       //     243,712 B
  float* mol     = (float*)(ws + 157369728);       //   1,024,000 B
  // cnt/cursor alias B2: only live before the first k_mm1 write to B2.
  int*   cnt     = (int*)B2;
  int*   cursor  = (int*)(ws + 128000000 + 204800);

  hipMemsetAsync(cnt, 0, N_NODES * sizeof(int), stream);
  k_tables<<<123, 128, 0, stream>>>(atom_table, bond_table, Wi, bi, Wu1, bu1,
                                    T1, U1, T2c, U2c);
  k_tt<<<476, 128, 0, stream>>>(T1, T2c, TT);
  k_wt<<<128, 128, 0, stream>>>(Wu2, Wt, Wlo);
  k_u1x<<<N_NODES / 4, 256, 0, stream>>>(x, U1, D);
  k_hist<<<N_EDGES / 256, 256, 0, stream>>>(eidx, cnt);
  k_scanA<<<49, 1024, 0, stream>>>(cnt, locinc, partial);
  k_scanB<<<1, 64, 0, stream>>>(partial, offs);
  k_scanC<<<(N_NODES + 255) / 256, 256, 0, stream>>>(cnt, locinc, offs, rowptr, cursor);
  k_fill<<<N_EDGES / 256, 256, 0, stream>>>(eidx, eattr, x, cursor, csr, csr0);
  k_molptr<<<(NUM_MOL + 256) / 256, 256, 0, stream>>>(batch, molptr);

  k_gather0<<<N_NODES / 4, 256, 0, stream>>>(rowptr, csr0, TT, A);

  for (int p = 0; p < 4; p++) {
    k_mm1<<<(N_NODES + 63) / 64, 256, 0, stream>>>(A, Wu1, D, B2);
    k_mm2<<<1024, 256, 0, stream>>>(B2, U2c, Wt, Wlo, bu2, M);
    k_gather<<<N_NODES / 4, 256, 0, stream>>>(rowptr, csr, M, A);
  }

  k_molgather<<<NUM_MOL / 4, 256, 0, stream>>>(A, molptr, mol);
  k_readout<<<NUM_MOL, 256, 0, stream>>>(mol, Wr1, br1, Wr2, br2, out);
}

// Round 13
// 737.858 us; speedup vs baseline: 1.2523x; 1.1182x over previous
//
#include <hip/hip_runtime.h>
#include <hip/hip_bf16.h>

#define N_NODES 50000
#define N_EDGES 800000
#define NUM_MOL 2000

typedef __attribute__((ext_vector_type(8))) short short8;
typedef __attribute__((ext_vector_type(4))) float f32x4;

union bfbits { __hip_bfloat16 b; short s; };

// ---------------------------------------------------------------------------
// Type tables.
// ---------------------------------------------------------------------------
__global__ void k_tables(const float* __restrict__ atom_table,
                         const float* __restrict__ bond_table,
                         const float* __restrict__ Wi,
                         const float* __restrict__ bi,
                         const float* __restrict__ Wu1,
                         const float* __restrict__ bu1,
                         float* __restrict__ T1, float* __restrict__ U1,
                         float* __restrict__ T2c, float* __restrict__ U2c) {
  int b = blockIdx.x;
  int c = threadIdx.x;
  if (b < 119) {
    float t = 0.f, u = 0.f;
    for (int k = 0; k < 128; k++) {
      float a = atom_table[b * 128 + k];
      t += a * Wi[k * 128 + c];
      u += a * Wu1[k * 128 + c];
    }
    T1[b * 128 + c] = t;
    U1[b * 128 + c] = u;
  } else {
    int a = b - 119;
    float t = bi[c], u = bu1[c];
    for (int k = 0; k < 64; k++) {
      float bv = bond_table[a * 64 + k];
      t += bv * Wi[(128 + k) * 128 + c];
      u += bv * Wu1[(128 + k) * 128 + c];
    }
    T2c[a * 128 + c] = t;
    U2c[a * 128 + c] = u;
  }
}

// TT[x*4+a, c] = relu(T1[x,c] + T2c[a,c])
__global__ void k_tt(const float* __restrict__ T1, const float* __restrict__ T2c,
                     float* __restrict__ TT) {
  int r = blockIdx.x;   // 0..475
  int c = threadIdx.x;
  float v = T1[(r >> 2) * 128 + c] + T2c[(r & 3) * 128 + c];
  TT[r * 128 + c] = v > 0.f ? v : 0.f;
}

// Wt/Wlo: hi/lo bf16 split of Wu2^T for MFMA B-frags.
__global__ void k_wt(const float* __restrict__ Wu2, short* __restrict__ Wt,
                     short* __restrict__ Wlo) {
  int n = blockIdx.x;
  int k = threadIdx.x;
  float w = Wu2[k * 128 + n];
  bfbits hi; hi.b = __float2bfloat16(w);
  float hf = __bfloat162float(hi.b);
  bfbits lo; lo.b = __float2bfloat16(w - hf);
  Wt[n * 128 + k] = hi.s;
  Wlo[n * 128 + k] = lo.s;
}

// W1t/W1lo: hi/lo bf16 split of Wu1[192:320,:]^T for mm1 MFMA B-frags.
__global__ void k_wt1(const float* __restrict__ Wu1, short* __restrict__ W1t,
                      short* __restrict__ W1lo) {
  int n = blockIdx.x;
  int k = threadIdx.x;
  float w = Wu1[(192 + k) * 128 + n];
  bfbits hi; hi.b = __float2bfloat16(w);
  float hf = __bfloat162float(hi.b);
  bfbits lo; lo.b = __float2bfloat16(w - hf);
  W1t[n * 128 + k] = hi.s;
  W1lo[n * 128 + k] = lo.s;
}

// D_[n] = U1[x[n]]  -- pass-invariant.
__global__ void k_u1x(const int* __restrict__ x, const float* __restrict__ U1,
                      float* __restrict__ D_) {
  int n = blockIdx.x * 4 + (threadIdx.x >> 6);
  int lane = threadIdx.x & 63;
  int xn = x[n];
  float2 v = *(const float2*)&U1[xn * 128 + lane * 2];
  *(float2*)&D_[n * 128 + lane * 2] = v;
}

// ---------------------------------------------------------------------------
// CSR build: histogram, 3-phase multi-block scan, fill (int2: {src*4+a, x4a}).
// ---------------------------------------------------------------------------
__global__ void k_hist(const int* __restrict__ eidx, int* __restrict__ cnt) {
  int e = blockIdx.x * 256 + threadIdx.x;
  atomicAdd(&cnt[eidx[N_EDGES + e]], 1);
}

__global__ __launch_bounds__(1024) void k_scanA(const int* __restrict__ cnt,
                                                int* __restrict__ locinc,
                                                int* __restrict__ partial) {
  __shared__ int buf[1024];
  int t = threadIdx.x;
  int i = blockIdx.x * 1024 + t;
  int v = (i < N_NODES) ? cnt[i] : 0;
  buf[t] = v;
  __syncthreads();
  for (int off = 1; off < 1024; off <<= 1) {
    int add = (t >= off) ? buf[t - off] : 0;
    __syncthreads();
    buf[t] += add;
    __syncthreads();
  }
  if (i < N_NODES) locinc[i] = buf[t];
  if (t == 1023) partial[blockIdx.x] = buf[t];
}

__global__ void k_scanB(const int* __restrict__ partial, int* __restrict__ offs) {
  int lane = threadIdx.x;   // 64 threads
  int v = (lane < 49) ? partial[lane] : 0;
  int inc = v;
  for (int d = 1; d < 64; d <<= 1) {
    int u = __shfl_up(inc, d, 64);
    if (lane >= d) inc += u;
  }
  if (lane < 49) offs[lane] = inc - v;   // exclusive
}

__global__ void k_scanC(const int* __restrict__ cnt, const int* __restrict__ locinc,
                        const int* __restrict__ offs,
                        int* __restrict__ rowptr, int* __restrict__ cursor) {
  int i = blockIdx.x * 256 + threadIdx.x;
  if (i < N_NODES) {
    int rp = locinc[i] + offs[i >> 10];
    rowptr[i + 1] = rp;
    cursor[i] = rp - cnt[i];
    if (i == 0) rowptr[0] = 0;
  }
}

__global__ void k_fill(const int* __restrict__ eidx, const int* __restrict__ attr,
                       const int* __restrict__ x,
                       int* __restrict__ cursor, int2* __restrict__ csr2) {
  int e = blockIdx.x * 256 + threadIdx.x;
  int d = eidx[N_EDGES + e];
  int s = eidx[e];
  int a = attr[e];
  int pos = atomicAdd(&cursor[d], 1);
  int2 v; v.x = s * 4 + a; v.y = x[s] * 4 + a;
  csr2[pos] = v;
}

// molptr[m] = lower_bound(batch, m)
__global__ void k_molptr(const int* __restrict__ batch, int* __restrict__ molptr) {
  int m = blockIdx.x * 256 + threadIdx.x;
  if (m > NUM_MOL) return;
  int lo = 0, hi = N_NODES;
  while (lo < hi) {
    int mid = (lo + hi) >> 1;
    if (batch[mid] < m) lo = mid + 1; else hi = mid;
  }
  molptr[m] = lo;
}

// ---------------------------------------------------------------------------
// Gather initial messages: 2 rows per VMEM inst, butterfly-32. idx = csr2.y
// ---------------------------------------------------------------------------
__global__ void k_gather0(const int* __restrict__ rowptr, const int2* __restrict__ csr2,
                          const float* __restrict__ TT, float* __restrict__ A_) {
  int n = blockIdx.x * 4 + (threadIdx.x >> 6);
  int lane = threadIdx.x & 63;
  int g = lane >> 5;        // 0..1
  int p = lane & 31;        // channel quad
  int beg = rowptr[n], end = rowptr[n + 1];
  float s0 = 0.f, s1 = 0.f, s2 = 0.f, s3 = 0.f;
  int i = beg;
  for (; i + 3 < end; i += 4) {
    int idxA = csr2[i + g].y;
    int idxB = csr2[i + 2 + g].y;
    float4 va = *(const float4*)&TT[idxA * 128 + p * 4];
    float4 vb = *(const float4*)&TT[idxB * 128 + p * 4];
    s0 += va.x + vb.x; s1 += va.y + vb.y;
    s2 += va.z + vb.z; s3 += va.w + vb.w;
  }
  for (; i < end; i += 2) {
    if (i + g < end) {
      int idx = csr2[i + g].y;
      float4 v = *(const float4*)&TT[idx * 128 + p * 4];
      s0 += v.x; s1 += v.y; s2 += v.z; s3 += v.w;
    }
  }
  s0 += __shfl_xor(s0, 32, 64);
  s1 += __shfl_xor(s1, 32, 64);
  s2 += __shfl_xor(s2, 32, 64);
  s3 += __shfl_xor(s3, 32, 64);
  float2 o;
  o.x = (g == 0) ? s0 : s2;
  o.y = (g == 0) ? s1 : s3;
  *(float2*)&A_[n * 128 + p * 4 + g * 2] = o;
}

// ---------------------------------------------------------------------------
// Gather messages: 4 rows per VMEM inst, butterflies 16/32. idx = csr2.x
// ---------------------------------------------------------------------------
__global__ void k_gather(const int* __restrict__ rowptr, const int2* __restrict__ csr2,
                         const __hip_bfloat16* __restrict__ M, float* __restrict__ A_) {
  int n = blockIdx.x * 4 + (threadIdx.x >> 6);
  int lane = threadIdx.x & 63;
  int g = lane >> 4;        // 0..3
  int p = lane & 15;        // channel octet
  int beg = rowptr[n], end = rowptr[n + 1];
  float s[8];
#pragma unroll
  for (int j = 0; j < 8; j++) s[j] = 0.f;
  const short* Ms = (const short*)M;
  int i = beg;
  for (; i + 7 < end; i += 8) {
    int idxA = csr2[i + g].x;
    int idxB = csr2[i + 4 + g].x;
    short8 va = *(const short8*)&Ms[idxA * 128 + p * 8];
    short8 vb = *(const short8*)&Ms[idxB * 128 + p * 8];
#pragma unroll
    for (int j = 0; j < 4; j++) {
      float2 fa = __bfloat1622float2(*(const __hip_bfloat162*)&((const short*)&va)[j * 2]);
      float2 fb = __bfloat1622float2(*(const __hip_bfloat162*)&((const short*)&vb)[j * 2]);
      s[j * 2] += fa.x + fb.x;
      s[j * 2 + 1] += fa.y + fb.y;
    }
  }
  for (; i < end; i += 4) {
    if (i + g < end) {
      int idx = csr2[i + g].x;
      short8 va = *(const short8*)&Ms[idx * 128 + p * 8];
#pragma unroll
      for (int j = 0; j < 4; j++) {
        float2 fa = __bfloat1622float2(*(const __hip_bfloat162*)&((const short*)&va)[j * 2]);
        s[j * 2] += fa.x;
        s[j * 2 + 1] += fa.y;
      }
    }
  }
#pragma unroll
  for (int j = 0; j < 8; j++) s[j] += __shfl_xor(s[j], 16, 64);
#pragma unroll
  for (int j = 0; j < 8; j++) s[j] += __shfl_xor(s[j], 32, 64);
  float2 o;
  o.x = s[g * 2];
  o.y = s[g * 2 + 1];
  *(float2*)&A_[n * 128 + p * 8 + g * 2] = o;
}

// ---------------------------------------------------------------------------
// k_mm1m (MFMA): B2 = A @ Wu1b + D. mm2-v7 structure: 2 waves/slab (16 nodes),
// 64 ch/wave, W hi/lo in VGPRs, A split hi/lo (3-term). Epilogue bounces
// fp32 acc through LDS, fuses the D add, stores coalesced float4.
// Grid 1024 x 2 iters covers 3125 slabs.
// ---------------------------------------------------------------------------
__global__ __launch_bounds__(256, 2) void k_mm1m(const float* __restrict__ A_,
                                                 const short* __restrict__ W1t,
                                                 const short* __restrict__ W1lo,
                                                 const float* __restrict__ D_,
                                                 float* __restrict__ B2_) {
  __shared__ float mbuf[2][16][132];
  int t = threadIdx.x;
  int lane = t & 63;
  int m = lane & 15;
  int quad = lane >> 4;
  int wid = t >> 6;
  int pairid = wid >> 1;
  int h = wid & 1;

  short8 whi[4][4], wlo[4][4];
#pragma unroll
  for (int kc = 0; kc < 4; kc++)
#pragma unroll
    for (int nt = 0; nt < 4; nt++) {
      int n = h * 64 + nt * 16 + m;
      whi[kc][nt] = *(const short8*)&W1t[n * 128 + kc * 32 + quad * 8];
      wlo[kc][nt] = *(const short8*)&W1lo[n * 128 + kc * 32 + quad * 8];
    }

  for (int iter = 0; iter < 2; iter++) {
    int s = iter * 2048 + blockIdx.x * 2 + pairid;
    if (s < 3125) {
      int row = s * 16 + m;   // global node for this lane's A fragment
      f32x4 acc[4];
#pragma unroll
      for (int nt = 0; nt < 4; nt++) acc[nt] = (f32x4){0.f, 0.f, 0.f, 0.f};

#pragma unroll
      for (int kc = 0; kc < 4; kc++) {
        int k0 = kc * 32 + quad * 8;
        short8 ahi, alo;
        {
          float av[8];
          *(float4*)&av[0] = *(const float4*)&A_[row * 128 + k0];
          *(float4*)&av[4] = *(const float4*)&A_[row * 128 + k0 + 4];
#pragma unroll
          for (int j = 0; j < 8; j++) {
            float hv = av[j];
            bfbits hi; hi.b = __float2bfloat16(hv);
            float hf = __bfloat162float(hi.b);
            bfbits lo; lo.b = __float2bfloat16(hv - hf);
            ahi[j] = hi.s;
            alo[j] = lo.s;
          }
        }
#pragma unroll
        for (int nt = 0; nt < 4; nt++) {
          acc[nt] = __builtin_amdgcn_mfma_f32_16x16x32_bf16(ahi, whi[kc][nt], acc[nt], 0, 0, 0);
          acc[nt] = __builtin_amdgcn_mfma_f32_16x16x32_bf16(alo, whi[kc][nt], acc[nt], 0, 0, 0);
          acc[nt] = __builtin_amdgcn_mfma_f32_16x16x32_bf16(ahi, wlo[kc][nt], acc[nt], 0, 0, 0);
        }
      }

#pragma unroll
      for (int nt = 0; nt < 4; nt++) {
#pragma unroll
        for (int r = 0; r < 4; r++)
          mbuf[pairid][quad * 4 + r][h * 64 + nt * 16 + m] = acc[nt][r];
      }
    }
    __syncthreads();
    // coalesced store with fused D add: 32 rows x 512 B = 1024 float4 chunks
#pragma unroll
    for (int p = 0; p < 4; p++) {
      int chunk = p * 256 + t;
      int row = chunk >> 5;          // 0..31
      int qf = chunk & 31;           // float4 index
      int sg = iter * 2048 + blockIdx.x * 2 + (row >> 4);
      if (sg < 3125) {
        int r = row & 15;
        int n = sg * 16 + r;
        float4 v = *(const float4*)&mbuf[row >> 4][r][qf * 4];
        float4 d = *(const float4*)&D_[n * 128 + qf * 4];
        v.x += d.x; v.y += d.y; v.z += d.z; v.w += d.w;
        *(float4*)&B2_[n * 128 + qf * 4] = v;
      }
    }
    __syncthreads();
  }
}

// ---------------------------------------------------------------------------
// k_mm2 v7 (unchanged from r12): H = relu(B2 + U2c); 3-term MFMA.
// ---------------------------------------------------------------------------
__global__ __launch_bounds__(256, 2) void k_mm2(const float* __restrict__ B2_,
                                                const float* __restrict__ U2c,
                                                const short* __restrict__ Wt,
                                                const short* __restrict__ Wlo,
                                                const float* __restrict__ bu2,
                                                __hip_bfloat16* __restrict__ M) {
  __shared__ short mbuf[2][16][132];
  int t = threadIdx.x;
  int lane = t & 63;
  int m = lane & 15;
  int quad = lane >> 4;
  int wid = t >> 6;
  int pairid = wid >> 1;
  int h = wid & 1;

  short8 whi[4][4], wlo[4][4];
#pragma unroll
  for (int kc = 0; kc < 4; kc++)
#pragma unroll
    for (int nt = 0; nt < 4; nt++) {
      int n = h * 64 + nt * 16 + m;
      whi[kc][nt] = *(const short8*)&Wt[n * 128 + kc * 32 + quad * 8];
      wlo[kc][nt] = *(const short8*)&Wlo[n * 128 + kc * 32 + quad * 8];
    }
  float bias[4];
#pragma unroll
  for (int nt = 0; nt < 4; nt++) bias[nt] = bu2[h * 64 + nt * 16 + m];

  for (int iter = 0; iter < 7; iter++) {
    int s = iter * 2048 + blockIdx.x * 2 + pairid;
    if (s < 12500) {
      int node = s * 4 + (m >> 2);
      int attr = m & 3;
      f32x4 acc[4];
#pragma unroll
      for (int nt = 0; nt < 4; nt++) acc[nt] = (f32x4){0.f, 0.f, 0.f, 0.f};

#pragma unroll
      for (int kc = 0; kc < 4; kc++) {
        int k0 = kc * 32 + quad * 8;
        short8 ahi, alo;
        {
          float bba[8], u2a[8];
          *(float4*)&bba[0] = *(const float4*)&B2_[node * 128 + k0];
          *(float4*)&bba[4] = *(const float4*)&B2_[node * 128 + k0 + 4];
          *(float4*)&u2a[0] = *(const float4*)&U2c[attr * 128 + k0];
          *(float4*)&u2a[4] = *(const float4*)&U2c[attr * 128 + k0 + 4];
#pragma unroll
          for (int j = 0; j < 8; j++) {
            float hv = bba[j] + u2a[j];
            hv = hv > 0.f ? hv : 0.f;
            bfbits hi; hi.b = __float2bfloat16(hv);
            float hf = __bfloat162float(hi.b);
            bfbits lo; lo.b = __float2bfloat16(hv - hf);
            ahi[j] = hi.s;
            alo[j] = lo.s;
          }
        }
#pragma unroll
        for (int nt = 0; nt < 4; nt++) {
          acc[nt] = __builtin_amdgcn_mfma_f32_16x16x32_bf16(ahi, whi[kc][nt], acc[nt], 0, 0, 0);
          acc[nt] = __builtin_amdgcn_mfma_f32_16x16x32_bf16(alo, whi[kc][nt], acc[nt], 0, 0, 0);
          acc[nt] = __builtin_amdgcn_mfma_f32_16x16x32_bf16(ahi, wlo[kc][nt], acc[nt], 0, 0, 0);
        }
      }

#pragma unroll
      for (int nt = 0; nt < 4; nt++) {
#pragma unroll
        for (int r = 0; r < 4; r++) {
          float v = acc[nt][r] + bias[nt];
          v = v > 0.f ? v : 0.f;
          bfbits o; o.b = __float2bfloat16(v);
          mbuf[pairid][quad * 4 + r][h * 64 + nt * 16 + m] = o.s;
        }
      }
    }
    __syncthreads();
#pragma unroll
    for (int p = 0; p < 2; p++) {
      int chunk = p * 256 + t;
      int row = chunk >> 4;
      int sg = iter * 2048 + blockIdx.x * 2 + (row >> 4);
      if (sg < 12500) {
        int r = row & 15;
        short8 v = *(const short8*)&mbuf[row >> 4][r][(chunk & 15) * 8];
        *(short8*)((short*)M + (sg * 16 + r) * 128 + (chunk & 15) * 8) = v;
      }
    }
    __syncthreads();
  }
}

// ---------------------------------------------------------------------------
// mol[m] = sum of A rows in [molptr[m], molptr[m+1]) — one wave per mol.
// ---------------------------------------------------------------------------
__global__ void k_molgather(const float* __restrict__ A_, const int* __restrict__ molptr,
                            float* __restrict__ mol) {
  int m = blockIdx.x * 4 + (threadIdx.x >> 6);
  int lane = threadIdx.x & 63;
  int beg = molptr[m], end = molptr[m + 1];
  float ax = 0.f, ay = 0.f;
  int n = beg;
  for (; n + 1 < end; n += 2) {
    float2 v0 = *(const float2*)&A_[n * 128 + lane * 2];
    float2 v1 = *(const float2*)&A_[(n + 1) * 128 + lane * 2];
    ax += v0.x + v1.x;
    ay += v0.y + v1.y;
  }
  if (n < end) {
    float2 v0 = *(const float2*)&A_[n * 128 + lane * 2];
    ax += v0.x;
    ay += v0.y;
  }
  float2 o; o.x = ax; o.y = ay;
  *(float2*)&mol[m * 128 + lane * 2] = o;
}

// ---------------------------------------------------------------------------
// out[m] = relu(mol[m] @ Wr1 + br1) @ Wr2 + br2
// ---------------------------------------------------------------------------
__global__ __launch_bounds__(256) void k_readout(const float* __restrict__ mol,
                                                 const float* __restrict__ Wr1,
                                                 const float* __restrict__ br1,
                                                 const float* __restrict__ Wr2,
                                                 const float* __restrict__ br2,
                                                 float* __restrict__ out) {
  int m = blockIdx.x;
  __shared__ float ms[128];
  __shared__ float red[256];
  int t = threadIdx.x;
  if (t < 128) ms[t] = mol[m * 128 + t];
  __syncthreads();
  float part = 0.f;
#pragma unroll
  for (int jj = 0; jj < 2; jj++) {
    int j = t + jj * 256;
    float acc = br1[j];
#pragma unroll
    for (int k = 0; k < 128; k += 4) {
      float4 m4 = *(const float4*)&ms[k];
      acc += m4.x * Wr1[k * 512 + j] + m4.y * Wr1[(k + 1) * 512 + j] +
             m4.z * Wr1[(k + 2) * 512 + j] + m4.w * Wr1[(k + 3) * 512 + j];
    }
    acc = acc > 0.f ? acc : 0.f;
    part += acc * Wr2[j];
  }
  red[t] = part;
  __syncthreads();
  for (int s = 128; s > 0; s >>= 1) {
    if (t < s) red[t] += red[t + s];
    __syncthreads();
  }
  if (t == 0) out[m] = red[0] + br2[0];
}

// ---------------------------------------------------------------------------
extern "C" void kernel_launch(void* const* d_in, const int* in_sizes, int n_in,
                              void* d_out, int out_size, void* d_ws, size_t ws_size,
                              hipStream_t stream) {
  const int* x        = (const int*)d_in[0];
  const int* eattr    = (const int*)d_in[1];
  const int* eidx     = (const int*)d_in[2];
  const int* batch    = (const int*)d_in[3];
  const float* atom_table = (const float*)d_in[4];
  const float* bond_table = (const float*)d_in[5];
  const float* Wi  = (const float*)d_in[6];
  const float* bi  = (const float*)d_in[7];
  const float* Wu1 = (const float*)d_in[8];
  const float* bu1 = (const float*)d_in[9];
  const float* Wu2 = (const float*)d_in[10];
  const float* bu2 = (const float*)d_in[11];
  const float* Wr1 = (const float*)d_in[12];
  const float* br1 = (const float*)d_in[13];
  const float* Wr2 = (const float*)d_in[14];
  const float* br2 = (const float*)d_in[15];
  float* out = (float*)d_out;

  char* ws = (char*)d_ws;
  __hip_bfloat16* M = (__hip_bfloat16*)(ws);       //  51,200,000 B (bf16)
  short* Wt      = (short*)(ws + 51200000);        //      32,768 B
  short* Wlo     = (short*)(ws + 51232768);        //      32,768 B
  short* W1t     = (short*)(ws + 51265536);        //      32,768 B
  short* W1lo    = (short*)(ws + 51298304);        //      32,768 B
  int*   locinc  = (int*)  (ws + 51331072);        //     200,000 B
  int*   partial = (int*)  (ws + 51531072);        //         256 B
  int*   offs    = (int*)  (ws + 51531328);        //         256 B
  int*   molptr  = (int*)  (ws + 51531584);        //       8,004 B
  int2*  csr2    = (int2*) (ws + 52000000);        //   6,400,000 B
  float* D       = (float*)(ws + 60000000);        //  25,600,000 B (U1[x[n]])
  float* A       = (float*)(ws + 102400000);       //  25,600,000 B
  float* B2      = (float*)(ws + 128000000);       //  25,600,000 B
  int*   rowptr  = (int*)  (ws + 156800000);       //     200,064 B
  float* T1      = (float*)(ws + 157000064);       //      60,928 B
  float* U1      = (float*)(ws + 157060992);       //      60,928 B
  float* T2c     = (float*)(ws + 157121920);       //       2,048 B
  float* U2c     = (float*)(ws + 157123968);       //       2,048 B
  float* TT      = (float*)(ws + 157126016);       //     243,712 B
  float* mol     = (float*)(ws + 157369728);       //   1,024,000 B
  // cnt/cursor alias B2: only live before the first k_mm1m write to B2.
  int*   cnt     = (int*)B2;
  int*   cursor  = (int*)(ws + 128000000 + 204800);

  hipMemsetAsync(cnt, 0, N_NODES * sizeof(int), stream);
  k_tables<<<123, 128, 0, stream>>>(atom_table, bond_table, Wi, bi, Wu1, bu1,
                                    T1, U1, T2c, U2c);
  k_tt<<<476, 128, 0, stream>>>(T1, T2c, TT);
  k_wt<<<128, 128, 0, stream>>>(Wu2, Wt, Wlo);
  k_wt1<<<128, 128, 0, stream>>>(Wu1, W1t, W1lo);
  k_u1x<<<N_NODES / 4, 256, 0, stream>>>(x, U1, D);
  k_hist<<<N_EDGES / 256, 256, 0, stream>>>(eidx, cnt);
  k_scanA<<<49, 1024, 0, stream>>>(cnt, locinc, partial);
  k_scanB<<<1, 64, 0, stream>>>(partial, offs);
  k_scanC<<<(N_NODES + 255) / 256, 256, 0, stream>>>(cnt, locinc, offs, rowptr, cursor);
  k_fill<<<N_EDGES / 256, 256, 0, stream>>>(eidx, eattr, x, cursor, csr2);
  k_molptr<<<(NUM_MOL + 256) / 256, 256, 0, stream>>>(batch, molptr);

  k_gather0<<<N_NODES / 4, 256, 0, stream>>>(rowptr, csr2, TT, A);

  for (int p = 0; p < 4; p++) {
    k_mm1m<<<1024, 256, 0, stream>>>(A, W1t, W1lo, D, B2);
    k_mm2<<<1024, 256, 0, stream>>>(B2, U2c, Wt, Wlo, bu2, M);
    k_gather<<<N_NODES / 4, 256, 0, stream>>>(rowptr, csr2, M, A);
  }

  k_molgather<<<NUM_MOL / 4, 256, 0, stream>>>(A, molptr, mol);
  k_readout<<<NUM_MOL, 256, 0, stream>>>(mol, Wr1, br1, Wr2, br2, out);
}

// Round 14
// 683.727 us; speedup vs baseline: 1.3515x; 1.0792x over previous
//
#include <hip/hip_runtime.h>
#include <hip/hip_bf16.h>

#define N_NODES 50000
#define N_EDGES 800000
#define NUM_MOL 2000

typedef __attribute__((ext_vector_type(8))) short short8;
typedef __attribute__((ext_vector_type(4))) float f32x4;

union bfbits { __hip_bfloat16 b; short s; };

// ---------------------------------------------------------------------------
// Type tables.
// ---------------------------------------------------------------------------
__global__ void k_tables(const float* __restrict__ atom_table,
                         const float* __restrict__ bond_table,
                         const float* __restrict__ Wi,
                         const float* __restrict__ bi,
                         const float* __restrict__ Wu1,
                         const float* __restrict__ bu1,
                         float* __restrict__ T1, float* __restrict__ U1,
                         float* __restrict__ T2c, float* __restrict__ U2c) {
  int b = blockIdx.x;
  int c = threadIdx.x;
  if (b < 119) {
    float t = 0.f, u = 0.f;
    for (int k = 0; k < 128; k++) {
      float a = atom_table[b * 128 + k];
      t += a * Wi[k * 128 + c];
      u += a * Wu1[k * 128 + c];
    }
    T1[b * 128 + c] = t;
    U1[b * 128 + c] = u;
  } else {
    int a = b - 119;
    float t = bi[c], u = bu1[c];
    for (int k = 0; k < 64; k++) {
      float bv = bond_table[a * 64 + k];
      t += bv * Wi[(128 + k) * 128 + c];
      u += bv * Wu1[(128 + k) * 128 + c];
    }
    T2c[a * 128 + c] = t;
    U2c[a * 128 + c] = u;
  }
}

// TT[x*4+a, c] = relu(T1[x,c] + T2c[a,c])
__global__ void k_tt(const float* __restrict__ T1, const float* __restrict__ T2c,
                     float* __restrict__ TT) {
  int r = blockIdx.x;   // 0..475
  int c = threadIdx.x;
  float v = T1[(r >> 2) * 128 + c] + T2c[(r & 3) * 128 + c];
  TT[r * 128 + c] = v > 0.f ? v : 0.f;
}

// Wt/Wlo: hi/lo bf16 split of Wu2^T for MFMA B-frags.
__global__ void k_wt(const float* __restrict__ Wu2, short* __restrict__ Wt,
                     short* __restrict__ Wlo) {
  int n = blockIdx.x;
  int k = threadIdx.x;
  float w = Wu2[k * 128 + n];
  bfbits hi; hi.b = __float2bfloat16(w);
  float hf = __bfloat162float(hi.b);
  bfbits lo; lo.b = __float2bfloat16(w - hf);
  Wt[n * 128 + k] = hi.s;
  Wlo[n * 128 + k] = lo.s;
}

// W1t/W1lo: hi/lo bf16 split of Wu1[192:320,:]^T for mm1 MFMA B-frags.
__global__ void k_wt1(const float* __restrict__ Wu1, short* __restrict__ W1t,
                      short* __restrict__ W1lo) {
  int n = blockIdx.x;
  int k = threadIdx.x;
  float w = Wu1[(192 + k) * 128 + n];
  bfbits hi; hi.b = __float2bfloat16(w);
  float hf = __bfloat162float(hi.b);
  bfbits lo; lo.b = __float2bfloat16(w - hf);
  W1t[n * 128 + k] = hi.s;
  W1lo[n * 128 + k] = lo.s;
}

// D_[n] = U1[x[n]]  -- pass-invariant.
__global__ void k_u1x(const int* __restrict__ x, const float* __restrict__ U1,
                      float* __restrict__ D_) {
  int n = blockIdx.x * 4 + (threadIdx.x >> 6);
  int lane = threadIdx.x & 63;
  int xn = x[n];
  float2 v = *(const float2*)&U1[xn * 128 + lane * 2];
  *(float2*)&D_[n * 128 + lane * 2] = v;
}

// ---------------------------------------------------------------------------
// CSR build: histogram, 3-phase multi-block scan, fill (int2: {src*4+a, x4a}).
// ---------------------------------------------------------------------------
__global__ void k_hist(const int* __restrict__ eidx, int* __restrict__ cnt) {
  int e = blockIdx.x * 256 + threadIdx.x;
  atomicAdd(&cnt[eidx[N_EDGES + e]], 1);
}

__global__ __launch_bounds__(1024) void k_scanA(const int* __restrict__ cnt,
                                                int* __restrict__ locinc,
                                                int* __restrict__ partial) {
  __shared__ int buf[1024];
  int t = threadIdx.x;
  int i = blockIdx.x * 1024 + t;
  int v = (i < N_NODES) ? cnt[i] : 0;
  buf[t] = v;
  __syncthreads();
  for (int off = 1; off < 1024; off <<= 1) {
    int add = (t >= off) ? buf[t - off] : 0;
    __syncthreads();
    buf[t] += add;
    __syncthreads();
  }
  if (i < N_NODES) locinc[i] = buf[t];
  if (t == 1023) partial[blockIdx.x] = buf[t];
}

__global__ void k_scanB(const int* __restrict__ partial, int* __restrict__ offs) {
  int lane = threadIdx.x;   // 64 threads
  int v = (lane < 49) ? partial[lane] : 0;
  int inc = v;
  for (int d = 1; d < 64; d <<= 1) {
    int u = __shfl_up(inc, d, 64);
    if (lane >= d) inc += u;
  }
  if (lane < 49) offs[lane] = inc - v;   // exclusive
}

__global__ void k_scanC(const int* __restrict__ cnt, const int* __restrict__ locinc,
                        const int* __restrict__ offs,
                        int* __restrict__ rowptr, int* __restrict__ cursor) {
  int i = blockIdx.x * 256 + threadIdx.x;
  if (i < N_NODES) {
    int rp = locinc[i] + offs[i >> 10];
    rowptr[i + 1] = rp;
    cursor[i] = rp - cnt[i];
    if (i == 0) rowptr[0] = 0;
  }
}

__global__ void k_fill(const int* __restrict__ eidx, const int* __restrict__ attr,
                       const int* __restrict__ x,
                       int* __restrict__ cursor, int2* __restrict__ csr2) {
  int e = blockIdx.x * 256 + threadIdx.x;
  int d = eidx[N_EDGES + e];
  int s = eidx[e];
  int a = attr[e];
  int pos = atomicAdd(&cursor[d], 1);
  int2 v; v.x = s * 4 + a; v.y = x[s] * 4 + a;
  csr2[pos] = v;
}

// molptr[m] = lower_bound(batch, m)
__global__ void k_molptr(const int* __restrict__ batch, int* __restrict__ molptr) {
  int m = blockIdx.x * 256 + threadIdx.x;
  if (m > NUM_MOL) return;
  int lo = 0, hi = N_NODES;
  while (lo < hi) {
    int mid = (lo + hi) >> 1;
    if (batch[mid] < m) lo = mid + 1; else hi = mid;
  }
  molptr[m] = lo;
}

// ---------------------------------------------------------------------------
// Gather initial messages: 2 rows per VMEM inst, butterfly-32. idx = csr2.y
// ---------------------------------------------------------------------------
__global__ void k_gather0(const int* __restrict__ rowptr, const int2* __restrict__ csr2,
                          const float* __restrict__ TT, float* __restrict__ A_) {
  int n = blockIdx.x * 4 + (threadIdx.x >> 6);
  int lane = threadIdx.x & 63;
  int g = lane >> 5;        // 0..1
  int p = lane & 31;        // channel quad
  int beg = rowptr[n], end = rowptr[n + 1];
  float s0 = 0.f, s1 = 0.f, s2 = 0.f, s3 = 0.f;
  int i = beg;
  for (; i + 3 < end; i += 4) {
    int idxA = csr2[i + g].y;
    int idxB = csr2[i + 2 + g].y;
    float4 va = *(const float4*)&TT[idxA * 128 + p * 4];
    float4 vb = *(const float4*)&TT[idxB * 128 + p * 4];
    s0 += va.x + vb.x; s1 += va.y + vb.y;
    s2 += va.z + vb.z; s3 += va.w + vb.w;
  }
  for (; i < end; i += 2) {
    if (i + g < end) {
      int idx = csr2[i + g].y;
      float4 v = *(const float4*)&TT[idx * 128 + p * 4];
      s0 += v.x; s1 += v.y; s2 += v.z; s3 += v.w;
    }
  }
  s0 += __shfl_xor(s0, 32, 64);
  s1 += __shfl_xor(s1, 32, 64);
  s2 += __shfl_xor(s2, 32, 64);
  s3 += __shfl_xor(s3, 32, 64);
  float2 o;
  o.x = (g == 0) ? s0 : s2;
  o.y = (g == 0) ? s1 : s3;
  *(float2*)&A_[n * 128 + p * 4 + g * 2] = o;
}

// ---------------------------------------------------------------------------
// Gather messages: 4 rows per VMEM inst, butterflies 16/32. idx = csr2.x
// ---------------------------------------------------------------------------
__global__ void k_gather(const int* __restrict__ rowptr, const int2* __restrict__ csr2,
                         const __hip_bfloat16* __restrict__ M, float* __restrict__ A_) {
  int n = blockIdx.x * 4 + (threadIdx.x >> 6);
  int lane = threadIdx.x & 63;
  int g = lane >> 4;        // 0..3
  int p = lane & 15;        // channel octet
  int beg = rowptr[n], end = rowptr[n + 1];
  float s[8];
#pragma unroll
  for (int j = 0; j < 8; j++) s[j] = 0.f;
  const short* Ms = (const short*)M;
  int i = beg;
  for (; i + 7 < end; i += 8) {
    int idxA = csr2[i + g].x;
    int idxB = csr2[i + 4 + g].x;
    short8 va = *(const short8*)&Ms[idxA * 128 + p * 8];
    short8 vb = *(const short8*)&Ms[idxB * 128 + p * 8];
#pragma unroll
    for (int j = 0; j < 4; j++) {
      float2 fa = __bfloat1622float2(*(const __hip_bfloat162*)&((const short*)&va)[j * 2]);
      float2 fb = __bfloat1622float2(*(const __hip_bfloat162*)&((const short*)&vb)[j * 2]);
      s[j * 2] += fa.x + fb.x;
      s[j * 2 + 1] += fa.y + fb.y;
    }
  }
  for (; i < end; i += 4) {
    if (i + g < end) {
      int idx = csr2[i + g].x;
      short8 va = *(const short8*)&Ms[idx * 128 + p * 8];
#pragma unroll
      for (int j = 0; j < 4; j++) {
        float2 fa = __bfloat1622float2(*(const __hip_bfloat162*)&((const short*)&va)[j * 2]);
        s[j * 2] += fa.x;
        s[j * 2 + 1] += fa.y;
      }
    }
  }
#pragma unroll
  for (int j = 0; j < 8; j++) s[j] += __shfl_xor(s[j], 16, 64);
#pragma unroll
  for (int j = 0; j < 8; j++) s[j] += __shfl_xor(s[j], 32, 64);
  float2 o;
  o.x = s[g * 2];
  o.y = s[g * 2 + 1];
  *(float2*)&A_[n * 128 + p * 8 + g * 2] = o;
}

// ---------------------------------------------------------------------------
// k_mm1m v2 (barrier-free MFMA): wave-task = (slab, half). Each wave computes
// 64 channels of a 16-node slab: B2 = A @ Wu1b + D. Transpose via PRIVATE
// per-wave LDS scratch (wave-synchronous, no __syncthreads), coalesced
// 16 B/lane stores with fused D add. 6250 tasks, grid-stride.
// ---------------------------------------------------------------------------
__global__ __launch_bounds__(256, 2) void k_mm1m(const float* __restrict__ A_,
                                                 const short* __restrict__ W1t,
                                                 const short* __restrict__ W1lo,
                                                 const float* __restrict__ D_,
                                                 float* __restrict__ B2_) {
  __shared__ float mbuf[4][16][68];
  int t = threadIdx.x;
  int lane = t & 63;
  int m = lane & 15;
  int quad = lane >> 4;
  int wslot = t >> 6;
  int w0 = blockIdx.x * 4 + wslot;   // global wave id (stride 4096 keeps parity)
  int h = w0 & 1;

  short8 whi[4][4], wlo[4][4];
#pragma unroll
  for (int kc = 0; kc < 4; kc++)
#pragma unroll
    for (int nt = 0; nt < 4; nt++) {
      int n = h * 64 + nt * 16 + m;
      whi[kc][nt] = *(const short8*)&W1t[n * 128 + kc * 32 + quad * 8];
      wlo[kc][nt] = *(const short8*)&W1lo[n * 128 + kc * 32 + quad * 8];
    }

  for (int tid = w0; tid < 6250; tid += 4096) {
    int s = tid >> 1;
    int row = s * 16 + m;   // node for this lane's A fragment
    f32x4 acc[4];
#pragma unroll
    for (int nt = 0; nt < 4; nt++) acc[nt] = (f32x4){0.f, 0.f, 0.f, 0.f};

#pragma unroll
    for (int kc = 0; kc < 4; kc++) {
      int k0 = kc * 32 + quad * 8;
      short8 ahi, alo;
      {
        float av[8];
        *(float4*)&av[0] = *(const float4*)&A_[row * 128 + k0];
        *(float4*)&av[4] = *(const float4*)&A_[row * 128 + k0 + 4];
#pragma unroll
        for (int j = 0; j < 8; j++) {
          float hv = av[j];
          bfbits hi; hi.b = __float2bfloat16(hv);
          float hf = __bfloat162float(hi.b);
          bfbits lo; lo.b = __float2bfloat16(hv - hf);
          ahi[j] = hi.s;
          alo[j] = lo.s;
        }
      }
#pragma unroll
      for (int nt = 0; nt < 4; nt++) {
        acc[nt] = __builtin_amdgcn_mfma_f32_16x16x32_bf16(ahi, whi[kc][nt], acc[nt], 0, 0, 0);
        acc[nt] = __builtin_amdgcn_mfma_f32_16x16x32_bf16(alo, whi[kc][nt], acc[nt], 0, 0, 0);
        acc[nt] = __builtin_amdgcn_mfma_f32_16x16x32_bf16(ahi, wlo[kc][nt], acc[nt], 0, 0, 0);
      }
    }

    // acc -> private LDS (local cols 0..63), wave-synchronous
#pragma unroll
    for (int nt = 0; nt < 4; nt++)
#pragma unroll
      for (int r = 0; r < 4; r++)
        mbuf[wslot][quad * 4 + r][nt * 16 + m] = acc[nt][r];
    // coalesced store with fused D add: 16 rows x 256 B = 256 float4 chunks
#pragma unroll
    for (int p = 0; p < 4; p++) {
      int c = p * 64 + lane;
      int rr = c >> 4;          // 0..15
      int qf = c & 15;          // float4 index within half-row
      int n = s * 16 + rr;
      float4 v = *(const float4*)&mbuf[wslot][rr][qf * 4];
      float4 d = *(const float4*)&D_[n * 128 + h * 64 + qf * 4];
      v.x += d.x; v.y += d.y; v.z += d.z; v.w += d.w;
      *(float4*)&B2_[n * 128 + h * 64 + qf * 4] = v;
    }
  }
}

// ---------------------------------------------------------------------------
// k_mm2 v8 (barrier-free MFMA): wave-task = (slab, half). H = relu(B2+U2c);
// D = ahi@Whi + alo@Whi + ahi@Wlo. Private per-wave LDS transpose, no
// __syncthreads. 25000 tasks, grid-stride.
// ---------------------------------------------------------------------------
__global__ __launch_bounds__(256, 2) void k_mm2(const float* __restrict__ B2_,
                                                const float* __restrict__ U2c,
                                                const short* __restrict__ Wt,
                                                const short* __restrict__ Wlo,
                                                const float* __restrict__ bu2,
                                                __hip_bfloat16* __restrict__ M) {
  __shared__ short mbuf[4][16][68];
  int t = threadIdx.x;
  int lane = t & 63;
  int m = lane & 15;
  int quad = lane >> 4;
  int wslot = t >> 6;
  int w0 = blockIdx.x * 4 + wslot;
  int h = w0 & 1;

  short8 whi[4][4], wlo[4][4];
#pragma unroll
  for (int kc = 0; kc < 4; kc++)
#pragma unroll
    for (int nt = 0; nt < 4; nt++) {
      int n = h * 64 + nt * 16 + m;
      whi[kc][nt] = *(const short8*)&Wt[n * 128 + kc * 32 + quad * 8];
      wlo[kc][nt] = *(const short8*)&Wlo[n * 128 + kc * 32 + quad * 8];
    }
  float bias[4];
#pragma unroll
  for (int nt = 0; nt < 4; nt++) bias[nt] = bu2[h * 64 + nt * 16 + m];

  for (int tid = w0; tid < 25000; tid += 4096) {
    int s = tid >> 1;
    int node = s * 4 + (m >> 2);
    int attr = m & 3;
    f32x4 acc[4];
#pragma unroll
    for (int nt = 0; nt < 4; nt++) acc[nt] = (f32x4){0.f, 0.f, 0.f, 0.f};

#pragma unroll
    for (int kc = 0; kc < 4; kc++) {
      int k0 = kc * 32 + quad * 8;
      short8 ahi, alo;
      {
        float bba[8], u2a[8];
        *(float4*)&bba[0] = *(const float4*)&B2_[node * 128 + k0];
        *(float4*)&bba[4] = *(const float4*)&B2_[node * 128 + k0 + 4];
        *(float4*)&u2a[0] = *(const float4*)&U2c[attr * 128 + k0];
        *(float4*)&u2a[4] = *(const float4*)&U2c[attr * 128 + k0 + 4];
#pragma unroll
        for (int j = 0; j < 8; j++) {
          float hv = bba[j] + u2a[j];
          hv = hv > 0.f ? hv : 0.f;
          bfbits hi; hi.b = __float2bfloat16(hv);
          float hf = __bfloat162float(hi.b);
          bfbits lo; lo.b = __float2bfloat16(hv - hf);
          ahi[j] = hi.s;
          alo[j] = lo.s;
        }
      }
#pragma unroll
      for (int nt = 0; nt < 4; nt++) {
        acc[nt] = __builtin_amdgcn_mfma_f32_16x16x32_bf16(ahi, whi[kc][nt], acc[nt], 0, 0, 0);
        acc[nt] = __builtin_amdgcn_mfma_f32_16x16x32_bf16(alo, whi[kc][nt], acc[nt], 0, 0, 0);
        acc[nt] = __builtin_amdgcn_mfma_f32_16x16x32_bf16(ahi, wlo[kc][nt], acc[nt], 0, 0, 0);
      }
    }

    // acc -> private LDS (bf16, local cols 0..63), wave-synchronous
#pragma unroll
    for (int nt = 0; nt < 4; nt++) {
#pragma unroll
      for (int r = 0; r < 4; r++) {
        float v = acc[nt][r] + bias[nt];
        v = v > 0.f ? v : 0.f;
        bfbits o; o.b = __float2bfloat16(v);
        mbuf[wslot][quad * 4 + r][nt * 16 + m] = o.s;
      }
    }
    // coalesced store: 16 half-rows x 128 B, one 16 B chunk per lane
    {
      int rr = lane >> 2;        // 0..15
      int qq = lane & 3;         // short8 index within half-row
      short8 v = *(const short8*)&mbuf[wslot][rr][qq * 8 + ((qq >> 2) * 0)];
      // (qq*8 covers shorts 0..31 of the 64-ch half? no: 4 qq * 8 = 32) --
      // need 64 shorts per half-row: 8 chunks -> 2 per lane
      *(short8*)((short*)M + (s * 16 + rr) * 128 + h * 64 + qq * 8) = v;
      short8 v2 = *(const short8*)&mbuf[wslot][rr][(qq + 4) * 8];
      *(short8*)((short*)M + (s * 16 + rr) * 128 + h * 64 + (qq + 4) * 8) = v2;
    }
  }
}

// ---------------------------------------------------------------------------
// mol[m] = sum of A rows in [molptr[m], molptr[m+1]) — one wave per mol.
// ---------------------------------------------------------------------------
__global__ void k_molgather(const float* __restrict__ A_, const int* __restrict__ molptr,
                            float* __restrict__ mol) {
  int m = blockIdx.x * 4 + (threadIdx.x >> 6);
  int lane = threadIdx.x & 63;
  int beg = molptr[m], end = molptr[m + 1];
  float ax = 0.f, ay = 0.f;
  int n = beg;
  for (; n + 1 < end; n += 2) {
    float2 v0 = *(const float2*)&A_[n * 128 + lane * 2];
    float2 v1 = *(const float2*)&A_[(n + 1) * 128 + lane * 2];
    ax += v0.x + v1.x;
    ay += v0.y + v1.y;
  }
  if (n < end) {
    float2 v0 = *(const float2*)&A_[n * 128 + lane * 2];
    ax += v0.x;
    ay += v0.y;
  }
  float2 o; o.x = ax; o.y = ay;
  *(float2*)&mol[m * 128 + lane * 2] = o;
}

// ---------------------------------------------------------------------------
// out[m] = relu(mol[m] @ Wr1 + br1) @ Wr2 + br2
// ---------------------------------------------------------------------------
__global__ __launch_bounds__(256) void k_readout(const float* __restrict__ mol,
                                                 const float* __restrict__ Wr1,
                                                 const float* __restrict__ br1,
                                                 const float* __restrict__ Wr2,
                                                 const float* __restrict__ br2,
                                                 float* __restrict__ out) {
  int m = blockIdx.x;
  __shared__ float ms[128];
  __shared__ float red[256];
  int t = threadIdx.x;
  if (t < 128) ms[t] = mol[m * 128 + t];
  __syncthreads();
  float part = 0.f;
#pragma unroll
  for (int jj = 0; jj < 2; jj++) {
    int j = t + jj * 256;
    float acc = br1[j];
#pragma unroll
    for (int k = 0; k < 128; k += 4) {
      float4 m4 = *(const float4*)&ms[k];
      acc += m4.x * Wr1[k * 512 + j] + m4.y * Wr1[(k + 1) * 512 + j] +
             m4.z * Wr1[(k + 2) * 512 + j] + m4.w * Wr1[(k + 3) * 512 + j];
    }
    acc = acc > 0.f ? acc : 0.f;
    part += acc * Wr2[j];
  }
  red[t] = part;
  __syncthreads();
  for (int s = 128; s > 0; s >>= 1) {
    if (t < s) red[t] += red[t + s];
    __syncthreads();
  }
  if (t == 0) out[m] = red[0] + br2[0];
}

// ---------------------------------------------------------------------------
extern "C" void kernel_launch(void* const* d_in, const int* in_sizes, int n_in,
                              void* d_out, int out_size, void* d_ws, size_t ws_size,
                              hipStream_t stream) {
  const int* x        = (const int*)d_in[0];
  const int* eattr    = (const int*)d_in[1];
  const int* eidx     = (const int*)d_in[2];
  const int* batch    = (const int*)d_in[3];
  const float* atom_table = (const float*)d_in[4];
  const float* bond_table = (const float*)d_in[5];
  const float* Wi  = (const float*)d_in[6];
  const float* bi  = (const float*)d_in[7];
  const float* Wu1 = (const float*)d_in[8];
  const float* bu1 = (const float*)d_in[9];
  const float* Wu2 = (const float*)d_in[10];
  const float* bu2 = (const float*)d_in[11];
  const float* Wr1 = (const float*)d_in[12];
  const float* br1 = (const float*)d_in[13];
  const float* Wr2 = (const float*)d_in[14];
  const float* br2 = (const float*)d_in[15];
  float* out = (float*)d_out;

  char* ws = (char*)d_ws;
  __hip_bfloat16* M = (__hip_bfloat16*)(ws);       //  51,200,000 B (bf16)
  short* Wt      = (short*)(ws + 51200000);        //      32,768 B
  short* Wlo     = (short*)(ws + 51232768);        //      32,768 B
  short* W1t     = (short*)(ws + 51265536);        //      32,768 B
  short* W1lo    = (short*)(ws + 51298304);        //      32,768 B
  int*   locinc  = (int*)  (ws + 51331072);        //     200,000 B
  int*   partial = (int*)  (ws + 51531072);        //         256 B
  int*   offs    = (int*)  (ws + 51531328);        //         256 B
  int*   molptr  = (int*)  (ws + 51531584);        //       8,004 B
  int2*  csr2    = (int2*) (ws + 52000000);        //   6,400,000 B
  float* D       = (float*)(ws + 60000000);        //  25,600,000 B (U1[x[n]])
  float* A       = (float*)(ws + 102400000);       //  25,600,000 B
  float* B2      = (float*)(ws + 128000000);       //  25,600,000 B
  int*   rowptr  = (int*)  (ws + 156800000);       //     200,064 B
  float* T1      = (float*)(ws + 157000064);       //      60,928 B
  float* U1      = (float*)(ws + 157060992);       //      60,928 B
  float* T2c     = (float*)(ws + 157121920);       //       2,048 B
  float* U2c     = (float*)(ws + 157123968);       //       2,048 B
  float* TT      = (float*)(ws + 157126016);       //     243,712 B
  float* mol     = (float*)(ws + 157369728);       //   1,024,000 B
  // cnt/cursor alias B2: only live before the first k_mm1m write to B2.
  int*   cnt     = (int*)B2;
  int*   cursor  = (int*)(ws + 128000000 + 204800);

  hipMemsetAsync(cnt, 0, N_NODES * sizeof(int), stream);
  k_tables<<<123, 128, 0, stream>>>(atom_table, bond_table, Wi, bi, Wu1, bu1,
                                    T1, U1, T2c, U2c);
  k_tt<<<476, 128, 0, stream>>>(T1, T2c, TT);
  k_wt<<<128, 128, 0, stream>>>(Wu2, Wt, Wlo);
  k_wt1<<<128, 128, 0, stream>>>(Wu1, W1t, W1lo);
  k_u1x<<<N_NODES / 4, 256, 0, stream>>>(x, U1, D);
  k_hist<<<N_EDGES / 256, 256, 0, stream>>>(eidx, cnt);
  k_scanA<<<49, 1024, 0, stream>>>(cnt, locinc, partial);
  k_scanB<<<1, 64, 0, stream>>>(partial, offs);
  k_scanC<<<(N_NODES + 255) / 256, 256, 0, stream>>>(cnt, locinc, offs, rowptr, cursor);
  k_fill<<<N_EDGES / 256, 256, 0, stream>>>(eidx, eattr, x, cursor, csr2);
  k_molptr<<<(NUM_MOL + 256) / 256, 256, 0, stream>>>(batch, molptr);

  k_gather0<<<N_NODES / 4, 256, 0, stream>>>(rowptr, csr2, TT, A);

  for (int p = 0; p < 4; p++) {
    k_mm1m<<<1024, 256, 0, stream>>>(A, W1t, W1lo, D, B2);
    k_mm2<<<1024, 256, 0, stream>>>(B2, U2c, Wt, Wlo, bu2, M);
    k_gather<<<N_NODES / 4, 256, 0, stream>>>(rowptr, csr2, M, A);
  }

  k_molgather<<<NUM_MOL / 4, 256, 0, stream>>>(A, molptr, mol);
  k_readout<<<NUM_MOL, 256, 0, stream>>>(mol, Wr1, br1, Wr2, br2, out);
}